// Round 5
// baseline (485.262 us; speedup 1.0000x reference)
//
#include <hip/hip_runtime.h>
#include <hip/hip_bf16.h>
#include <math.h>
#include <stdint.h>

#define B_ 4
#define D_ 64
#define H_ 64
#define W_ 64
#define S_ 64
#define N_ 8192
#define K_ 4
#define HID_ 256
#define HW_ 4096
#define NQ_ (B_*N_)        // 32768 queries
#define ROWS_ (NQ_*8)      // 262144 MLP rows (4 attn + 4 local per query)

typedef _Float16 h8   __attribute__((ext_vector_type(8)));
typedef float    f32x4 __attribute__((ext_vector_type(4)));

// ---------------------------------------------------------------------------
// prep: transpose feat -> featT[b][y][x][c] (f16); build reordered/transposed
// weights: w0rT[n][k=kk*64+cc] (f16), wT123[l][n][k] (f16), w4T[j][c] (f32),
// w0tail[j][n] (f32)
// ---------------------------------------------------------------------------
__global__ void prep_kernel(const float* __restrict__ feat,
                            const float* __restrict__ w0,
                            const float* __restrict__ w1,
                            const float* __restrict__ w2,
                            const float* __restrict__ w3,
                            const float* __restrict__ w4,
                            _Float16* __restrict__ featT,
                            _Float16* __restrict__ w0rT,
                            _Float16* __restrict__ wT123,
                            float* __restrict__ w4T,
                            float* __restrict__ w0tail)
{
  int i = blockIdx.x * 256 + threadIdx.x;
  if (i < 1048576) {                       // featT, dest-linear (b,y,x,c)
    int c = i & 63, x = (i >> 6) & 63, y = (i >> 12) & 63, b = i >> 18;
    featT[i] = (_Float16)feat[(((b << 6) + c) << 12) + (y << 6) + x];
    return;
  }
  i -= 1048576;
  if (i < 147456) {                        // w0rT[n][k], k = kk*64+cc <- w0[cc*9+kk][n]
    int n = i / 576, k = i - n * 576;
    int kk = k >> 6, cc = k & 63;
    w0rT[i] = (_Float16)w0[(cc * 9 + kk) * 256 + n];
    return;
  }
  i -= 147456;
  if (i < 196608) {                        // wT123[l][n][k] <- w_l[k][n]
    int l = i >> 16, rem = i & 65535, n = rem >> 8, k = rem & 255;
    const float* w = (l == 0) ? w1 : (l == 1) ? w2 : w3;
    wT123[i] = (_Float16)w[k * 256 + n];
    return;
  }
  i -= 196608;
  if (i < 768) { int j = i / 256, c = i - j * 256; w4T[i] = w4[c * 3 + j]; return; }
  i -= 768;
  if (i < 1024) { int j = i >> 8, n = i & 255; w0tail[i] = w0[(576 + j) * 256 + n]; }
}

// ---------------------------------------------------------------------------
// segmax: argmax over S (first occurrence) per (b, pixel)
// ---------------------------------------------------------------------------
__global__ void segmax_kernel(const float* __restrict__ attn, int* __restrict__ segm)
{
  int t = blockIdx.x * 256 + threadIdx.x;
  if (t >= B_ * HW_) return;
  const float* a = attn + (size_t)t * S_;
  float best = a[0]; int bi = 0;
  for (int s = 1; s < S_; ++s) { float v = a[s]; if (v > best) { best = v; bi = s; } }
  segm[t] = bi;
}

// ---------------------------------------------------------------------------
// topk: per (b,s) block, top-4 of attn[b, :, s] over 4096 pixels.
// Tie semantics: sorted descending, equal values -> lower index first.
// ---------------------------------------------------------------------------
__global__ void topk_kernel(const float* __restrict__ attn,
                            int* __restrict__ refc, float* __restrict__ wprob)
{
  int bid = blockIdx.x;                 // b*64 + s
  int b = bid >> 6, s = bid & 63;
  int tid = threadIdx.x;
  __shared__ float sv[256]; __shared__ int si[256];
  __shared__ float cvs[4]; __shared__ int cis[4];

  float tv[4] = { -INFINITY, -INFINITY, -INFINITY, -INFINITY };
  int   ti[4] = { 0x7fffffff, 0x7fffffff, 0x7fffffff, 0x7fffffff };
  for (int j = tid; j < HW_; j += 256) {
    float v = attn[((size_t)b * HW_ + j) * S_ + s];
    if (v > tv[3]) {                    // equal value: existing (lower idx) wins
      tv[3] = v; ti[3] = j;
      #pragma unroll
      for (int x = 3; x > 0; --x) {
        if (tv[x] > tv[x-1] || (tv[x] == tv[x-1] && ti[x] < ti[x-1])) {
          float fv = tv[x]; tv[x] = tv[x-1]; tv[x-1] = fv;
          int   fi = ti[x]; ti[x] = ti[x-1]; ti[x-1] = fi;
        }
      }
    }
  }
  int ptr = 0;
  for (int r = 0; r < 4; ++r) {
    sv[tid] = (ptr < 4) ? tv[ptr] : -INFINITY;
    si[tid] = (ptr < 4) ? ti[ptr] : 0x7fffffff;
    __syncthreads();
    for (int o = 128; o; o >>= 1) {
      if (tid < o) {
        float v2 = sv[tid + o]; int i2 = si[tid + o];
        if (v2 > sv[tid] || (v2 == sv[tid] && i2 < si[tid])) { sv[tid] = v2; si[tid] = i2; }
      }
      __syncthreads();
    }
    if (tid == 0) { cvs[r] = sv[0]; cis[r] = si[0]; }
    __syncthreads();
    if (ptr < 4 && ti[ptr] == cis[r]) ptr++;
    __syncthreads();
  }
  if (tid == 0) {
    float ssum = cvs[0] + cvs[1] + cvs[2] + cvs[3];
    for (int k = 0; k < 4; ++k) { refc[bid*4 + k] = cis[k]; wprob[bid*4 + k] = cvs[k] / ssum; }
  }
}

// ---------------------------------------------------------------------------
// meta: per query build 8 MLP-row descriptors {src pixel-row, tail t[4], weight}
// ---------------------------------------------------------------------------
__global__ void meta_kernel(const float* __restrict__ coord, const float* __restrict__ cell,
                            const int* __restrict__ segm, const int* __restrict__ refc,
                            const float* __restrict__ wprob,
                            int* __restrict__ msrc, float4* __restrict__ mt,
                            float* __restrict__ mwgt)
{
  int q = blockIdx.x * 256 + threadIdx.x;
  if (q >= NQ_) return;
  int b = q >> 13;
  float c0 = coord[2*q], c1 = coord[2*q + 1];
  float rc0 = cell[2*q] * 64.0f, rc1 = cell[2*q + 1] * 64.0f;   // rel_cell

  // ---- attention branch ----
  float pf0 = (c0 + 1.0f) / 2.0f * 64.0f;
  float pf1 = (c1 + 1.0f) / 2.0f * 64.0f;
  int pc0 = (int)pf0, pc1 = (int)pf1;           // trunc (non-negative)
  pc0 = min(max(pc0, 0), 4095); pc1 = min(max(pc1, 0), 4095);
  int pc1d = pc0 * 64 + pc1;
  int sg = segm[b * 4096 + min(pc1d, 4095)];
  int base = (b * 64 + sg) * 4;
  #pragma unroll
  for (int k = 0; k < 4; ++k) {
    int rc = refc[base + k];
    int rrc = rc - pc1d;
    float rel0 = (float)(rrc >> 6) * 0.015625f;   // floor-div by 64 then /64
    float rel1 = (float)(rrc & 63) * 0.015625f;
    int r = q * 8 + k;
    msrc[r] = rc;                                  // batch-0 gather (faithful)
    mt[r] = make_float4(rel0, rel1, rc0, rc1);
    mwgt[r] = 0.5f * wprob[base + k];
  }

  // ---- local ensemble branch ----
  const float sg0[4] = { -1.f, -1.f, 1.f, 1.f };
  const float sg1[4] = { -1.f,  1.f, -1.f, 1.f };
  float area[4], rr0[4], rr1[4]; int srcs[4];
  #pragma unroll
  for (int t = 0; t < 4; ++t) {
    float o0 = sg0[t] * 0.015625f + 1e-6f;
    float o1 = sg1[t] * 0.015625f + 1e-6f;
    float cc0 = fminf(fmaxf(c0 + o0, -1.0f + 1e-6f), 1.0f - 1e-6f);
    float cc1 = fminf(fmaxf(c1 + o1, -1.0f + 1e-6f), 1.0f - 1e-6f);
    float vy = ((cc0 + 1.0f) * 64.0f - 1.0f) / 2.0f;
    float vx = ((cc1 + 1.0f) * 64.0f - 1.0f) / 2.0f;
    float fy = fminf(fmaxf(rintf(vy), 0.0f), 63.0f);   // rint (RNE) then clip
    float fx = fminf(fmaxf(rintf(vx), 0.0f), 63.0f);
    int iy = (int)fy, ix = (int)fx;
    srcs[t] = b * 4096 + iy * 64 + ix;
    float qc0 = -1.0f + (2.0f * (float)iy + 1.0f) / 64.0f;
    float qc1 = -1.0f + (2.0f * (float)ix + 1.0f) / 64.0f;
    float r0 = (c0 - qc0) * 64.0f;
    float r1 = (c1 - qc1) * 64.0f;
    rr0[t] = r0; rr1[t] = r1;
    area[t] = fabsf(r0 * r1) + 1e-9f;
  }
  float tot = area[0] + area[1] + area[2] + area[3];
  #pragma unroll
  for (int t = 0; t < 4; ++t) {
    int r = q * 8 + 4 + t;
    msrc[r] = srcs[t];
    mt[r] = make_float4(rr0[t], rr1[t], rc0, rc1);
    mwgt[r] = 0.5f * area[3 - t] / tot;            // wts = area[::-1]/tot
  }
}

// ---------------------------------------------------------------------------
// P0 GEMM (f16 MFMA): P0[b*hw+p][n] = sum_{k<576} unfold(feat)[p][k] * w0[k][n]
// Block: one image row (64 pixels) x 256 cols; 4 waves x 64 cols.
// ---------------------------------------------------------------------------
__launch_bounds__(256, 2)
__global__ void p0_kernel(const _Float16* __restrict__ featT,
                          const _Float16* __restrict__ w0rT,
                          float* __restrict__ P0)
{
  int blk = blockIdx.x;                 // b*64 + y
  int b = blk >> 6, y = blk & 63;
  int tid = threadIdx.x;
  int wave = tid >> 6, lane = tid & 63, quad = lane >> 4, l16 = lane & 15;
  int colbase = wave * 64;

  f32x4 acc[4][4];
  #pragma unroll
  for (int i = 0; i < 4; i++)
    #pragma unroll
    for (int j = 0; j < 4; j++) { f32x4 z = {0.f,0.f,0.f,0.f}; acc[i][j] = z; }
  h8 zero8 = {0,0,0,0,0,0,0,0};

  for (int ks = 0; ks < 18; ++ks) {     // K = 576 = 18*32
    int k0 = ks * 32 + quad * 8;
    int kk = k0 >> 6, cc = k0 & 63;
    int di = kk / 3 - 1, dj = kk - (kk / 3) * 3 - 1;
    int yy = y + di;
    h8 afr[4];
    #pragma unroll
    for (int rb = 0; rb < 4; rb++) {
      int x = rb * 16 + l16;
      int xx = x + dj;
      if ((unsigned)yy < 64u && (unsigned)xx < 64u)
        afr[rb] = *(const h8*)(featT + ((((size_t)b * 64 + yy) * 64 + xx) * 64 + cc));
      else
        afr[rb] = zero8;
    }
    h8 bfr[4];
    #pragma unroll
    for (int cb = 0; cb < 4; cb++) {
      int n = colbase + cb * 16 + l16;
      bfr[cb] = *(const h8*)(w0rT + (size_t)n * 576 + k0);
    }
    #pragma unroll
    for (int rb = 0; rb < 4; rb++)
      #pragma unroll
      for (int cb = 0; cb < 4; cb++)
        acc[rb][cb] = __builtin_amdgcn_mfma_f32_16x16x32_f16(afr[rb], bfr[cb], acc[rb][cb], 0, 0, 0);
  }
  int pixbase = blk * 64;
  #pragma unroll
  for (int rb = 0; rb < 4; rb++)
    #pragma unroll
    for (int cb = 0; cb < 4; cb++)
      #pragma unroll
      for (int i = 0; i < 4; i++) {
        int m = rb * 16 + quad * 4 + i;
        int n = colbase + cb * 16 + l16;
        P0[((size_t)pixbase + m) * 256 + n] = acc[rb][cb][i];
      }
}

// ---------------------------------------------------------------------------
// Fused MLP trunk (f16 MFMA): seed (P0 gather + tail) -> 3x (256x256 MFMA +
// relu, LDS ping-pong) -> 256->3 epilogue -> 8-row weighted reduction -> f32.
// 64 rows / block, 4 waves x 64 cols.
// ---------------------------------------------------------------------------
__launch_bounds__(256, 2)
__global__ void trunk_kernel(const float* __restrict__ P0,
                             const int* __restrict__ msrc,
                             const float4* __restrict__ mt,
                             const float* __restrict__ mwgt,
                             const float* __restrict__ w0tail,
                             const float* __restrict__ b0,
                             const _Float16* __restrict__ wT123,
                             const float* __restrict__ b1,
                             const float* __restrict__ b2,
                             const float* __restrict__ b3,
                             const float* __restrict__ w4T,
                             const float* __restrict__ b4,
                             float* __restrict__ out)
{
  __shared__ _Float16 hA[64][264];      // +8 pad: 2-way (free) LDS pattern
  __shared__ _Float16 hB[64][264];
  __shared__ float part_s[64][4][4];
  __shared__ float red[64][4];

  int tid = threadIdx.x;
  int rowbase = blockIdx.x * 64;

  // ---- seed: h0 = relu(P0[src] + t . w0tail + b0) ----
  {
    int cg = tid & 63;
    float4 wt0 = ((const float4*)w0tail)[cg];
    float4 wt1 = ((const float4*)w0tail)[64 + cg];
    float4 wt2 = ((const float4*)w0tail)[128 + cg];
    float4 wt3 = ((const float4*)w0tail)[192 + cg];
    float4 bb  = ((const float4*)b0)[cg];
    for (int rr = tid >> 6; rr < 64; rr += 4) {
      int r = rowbase + rr;
      int src = msrc[r];
      float4 t = mt[r];
      float4 p = ((const float4*)(P0 + (size_t)src * 256))[cg];
      float v0 = p.x + t.x*wt0.x + t.y*wt1.x + t.z*wt2.x + t.w*wt3.x + bb.x;
      float v1 = p.y + t.x*wt0.y + t.y*wt1.y + t.z*wt2.y + t.w*wt3.y + bb.y;
      float v2 = p.z + t.x*wt0.z + t.y*wt1.z + t.z*wt2.z + t.w*wt3.z + bb.z;
      float v3 = p.w + t.x*wt0.w + t.y*wt1.w + t.z*wt2.w + t.w*wt3.w + bb.w;
      hA[rr][cg*4 + 0] = (_Float16)fmaxf(v0, 0.0f);
      hA[rr][cg*4 + 1] = (_Float16)fmaxf(v1, 0.0f);
      hA[rr][cg*4 + 2] = (_Float16)fmaxf(v2, 0.0f);
      hA[rr][cg*4 + 3] = (_Float16)fmaxf(v3, 0.0f);
    }
  }
  __syncthreads();

  int wave = tid >> 6, lane = tid & 63, quad = lane >> 4, l16 = lane & 15;
  _Float16 (*hin)[264] = hA; _Float16 (*hout)[264] = hB;

  #pragma unroll 1
  for (int l = 0; l < 3; ++l) {
    const _Float16* wT = wT123 + (size_t)l * 65536;
    const float* bia = (l == 0) ? b1 : (l == 1) ? b2 : b3;
    f32x4 acc[4][4];
    #pragma unroll
    for (int i = 0; i < 4; i++)
      #pragma unroll
      for (int j = 0; j < 4; j++) { f32x4 z = {0.f,0.f,0.f,0.f}; acc[i][j] = z; }
    #pragma unroll
    for (int ks = 0; ks < 8; ++ks) {
      int k0 = ks * 32 + quad * 8;
      h8 afr[4], bfr[4];
      #pragma unroll
      for (int rb = 0; rb < 4; rb++)
        afr[rb] = *(const h8*)(&hin[rb * 16 + l16][k0]);
      #pragma unroll
      for (int cb = 0; cb < 4; cb++) {
        int n = wave * 64 + cb * 16 + l16;
        bfr[cb] = *(const h8*)(wT + (size_t)n * 256 + k0);
      }
      #pragma unroll
      for (int rb = 0; rb < 4; rb++)
        #pragma unroll
        for (int cb = 0; cb < 4; cb++)
          acc[rb][cb] = __builtin_amdgcn_mfma_f32_16x16x32_f16(afr[rb], bfr[cb], acc[rb][cb], 0, 0, 0);
    }
    __syncthreads();                    // everyone done reading hin
    #pragma unroll
    for (int rb = 0; rb < 4; rb++)
      #pragma unroll
      for (int cb = 0; cb < 4; cb++) {
        int n = wave * 64 + cb * 16 + l16;
        float bv = bia[n];
        #pragma unroll
        for (int i = 0; i < 4; i++) {
          int m = rb * 16 + quad * 4 + i;
          hout[m][n] = (_Float16)fmaxf(acc[rb][cb][i] + bv, 0.0f);
        }
      }
    __syncthreads();                    // writes visible before next reads
    _Float16 (*tmp)[264] = hin; hin = hout; hout = tmp;
  }

  // ---- epilogue: y = h3 @ w4 + b4, weight, reduce 8 rows/query ----
  {
    int row = tid >> 2, part = tid & 3;
    const _Float16* hr = &hin[row][part * 64];
    float s0 = 0.f, s1 = 0.f, s2 = 0.f;
    #pragma unroll
    for (int c8 = 0; c8 < 64; c8 += 8) {
      h8 hv = *(const h8*)(hr + c8);
      #pragma unroll
      for (int u = 0; u < 8; ++u) {
        float h = (float)hv[u];
        int c = part * 64 + c8 + u;
        s0 += h * w4T[c];
        s1 += h * w4T[256 + c];
        s2 += h * w4T[512 + c];
      }
    }
    part_s[row][part][0] = s0; part_s[row][part][1] = s1; part_s[row][part][2] = s2;
  }
  __syncthreads();
  if (tid < 64) {
    float wgt = mwgt[rowbase + tid];
    red[tid][0] = (part_s[tid][0][0] + part_s[tid][1][0] + part_s[tid][2][0] + part_s[tid][3][0] + b4[0]) * wgt;
    red[tid][1] = (part_s[tid][0][1] + part_s[tid][1][1] + part_s[tid][2][1] + part_s[tid][3][1] + b4[1]) * wgt;
    red[tid][2] = (part_s[tid][0][2] + part_s[tid][1][2] + part_s[tid][2][2] + part_s[tid][3][2] + b4[2]) * wgt;
  }
  __syncthreads();
  if (tid < 8) {
    int q = (rowbase >> 3) + tid;       // global query index b*N+n
    float o0 = 0.f, o1 = 0.f, o2 = 0.f;
    #pragma unroll
    for (int j = 0; j < 8; j++) {
      o0 += red[tid * 8 + j][0];
      o1 += red[tid * 8 + j][1];
      o2 += red[tid * 8 + j][2];
    }
    out[q * 3 + 0] = o0;                // FLOAT32 output (reference dtype)
    out[q * 3 + 1] = o1;
    out[q * 3 + 2] = o2;
  }
}

// ---------------------------------------------------------------------------
extern "C" void kernel_launch(void* const* d_in, const int* in_sizes, int n_in,
                              void* d_out, int out_size, void* d_ws, size_t ws_size,
                              hipStream_t stream)
{
  const float* feat  = (const float*)d_in[0];
  const float* attn  = (const float*)d_in[1];
  const float* coord = (const float*)d_in[2];
  const float* cell  = (const float*)d_in[3];
  const float* w0 = (const float*)d_in[4];
  const float* b0 = (const float*)d_in[5];
  const float* w1 = (const float*)d_in[6];
  const float* b1 = (const float*)d_in[7];
  const float* w2 = (const float*)d_in[8];
  const float* b2 = (const float*)d_in[9];
  const float* w3 = (const float*)d_in[10];
  const float* b3 = (const float*)d_in[11];
  const float* w4 = (const float*)d_in[12];
  const float* b4 = (const float*)d_in[13];
  float* out = (float*)d_out;           // reference output dtype = float32

  char* ws = (char*)d_ws;
  size_t off = 0;
  auto alloc = [&](size_t bytes) -> char* {
    char* p = ws + off;
    off += (bytes + 255) & ~(size_t)255;
    return p;
  };
  _Float16* featT = (_Float16*)alloc((size_t)B_ * H_ * W_ * D_ * 2);  //  2.10 MB
  _Float16* w0rT  = (_Float16*)alloc((size_t)256 * 576 * 2);          //  0.29 MB
  _Float16* wT123 = (_Float16*)alloc((size_t)3 * 256 * 256 * 2);      //  0.39 MB
  float*  w4T   = (float*)alloc((size_t)3 * 256 * 4);
  float*  w0tl  = (float*)alloc((size_t)4 * 256 * 4);
  int*    segm  = (int*)alloc((size_t)B_ * HW_ * 4);                  //  64 KB
  int*    refc  = (int*)alloc((size_t)B_ * S_ * K_ * 4);
  float*  wprob = (float*)alloc((size_t)B_ * S_ * K_ * 4);
  float*  P0    = (float*)alloc((size_t)B_ * HW_ * 256 * 4);          // 16.8 MB
  int*    msrc  = (int*)alloc((size_t)ROWS_ * 4);                     //  1.0 MB
  float4* mtb   = (float4*)alloc((size_t)ROWS_ * 16);                 //  4.2 MB
  float*  mwgt  = (float*)alloc((size_t)ROWS_ * 4);                   //  1.0 MB
  (void)in_sizes; (void)n_in; (void)out_size; (void)ws_size;          // ~26 MB total

  prep_kernel<<<(1394432 + 255) / 256, 256, 0, stream>>>(feat, w0, w1, w2, w3, w4,
                                                         featT, w0rT, wT123, w4T, w0tl);
  segmax_kernel<<<64, 256, 0, stream>>>(attn, segm);
  topk_kernel<<<256, 256, 0, stream>>>(attn, refc, wprob);
  meta_kernel<<<128, 256, 0, stream>>>(coord, cell, segm, refc, wprob, msrc, mtb, mwgt);
  p0_kernel<<<256, 256, 0, stream>>>(featT, w0rT, P0);
  trunk_kernel<<<4096, 256, 0, stream>>>(P0, msrc, mtb, mwgt, w0tl, b0, wT123,
                                         b1, b2, b3, w4T, b4, out);
}

// Round 6
// 464.348 us; speedup vs baseline: 1.0450x; 1.0450x over previous
//
#include <hip/hip_runtime.h>
#include <hip/hip_bf16.h>
#include <math.h>
#include <stdint.h>

#define B_ 4
#define D_ 64
#define H_ 64
#define W_ 64
#define S_ 64
#define N_ 8192
#define K_ 4
#define HID_ 256
#define HW_ 4096
#define NQ_ (B_*N_)        // 32768 queries
#define ROWS_ (NQ_*8)      // 262144 MLP rows (4 attn + 4 local per query)

typedef _Float16 h8   __attribute__((ext_vector_type(8)));
typedef _Float16 h4   __attribute__((ext_vector_type(4)));
typedef float    f32x4 __attribute__((ext_vector_type(4)));

// ---------------------------------------------------------------------------
// prep: transpose feat -> featT[b][y][x][c] (f16); build reordered/transposed
// weights: w0rT[n][k=kk*64+cc] (f16), wT123[l][n][k] (f16), w4T[j][c] (f32),
// w0tail[j][n] (f32)
// ---------------------------------------------------------------------------
__global__ void prep_kernel(const float* __restrict__ feat,
                            const float* __restrict__ w0,
                            const float* __restrict__ w1,
                            const float* __restrict__ w2,
                            const float* __restrict__ w3,
                            const float* __restrict__ w4,
                            _Float16* __restrict__ featT,
                            _Float16* __restrict__ w0rT,
                            _Float16* __restrict__ wT123,
                            float* __restrict__ w4T,
                            float* __restrict__ w0tail)
{
  int i = blockIdx.x * 256 + threadIdx.x;
  if (i < 1048576) {                       // featT, dest-linear (b,y,x,c)
    int c = i & 63, x = (i >> 6) & 63, y = (i >> 12) & 63, b = i >> 18;
    featT[i] = (_Float16)feat[(((b << 6) + c) << 12) + (y << 6) + x];
    return;
  }
  i -= 1048576;
  if (i < 147456) {                        // w0rT[n][k], k = kk*64+cc <- w0[cc*9+kk][n]
    int n = i / 576, k = i - n * 576;
    int kk = k >> 6, cc = k & 63;
    w0rT[i] = (_Float16)w0[(cc * 9 + kk) * 256 + n];
    return;
  }
  i -= 147456;
  if (i < 196608) {                        // wT123[l][n][k] <- w_l[k][n]
    int l = i >> 16, rem = i & 65535, n = rem >> 8, k = rem & 255;
    const float* w = (l == 0) ? w1 : (l == 1) ? w2 : w3;
    wT123[i] = (_Float16)w[k * 256 + n];
    return;
  }
  i -= 196608;
  if (i < 768) { int j = i / 256, c = i - j * 256; w4T[i] = w4[c * 3 + j]; return; }
  i -= 768;
  if (i < 1024) { int j = i >> 8, n = i & 255; w0tail[i] = w0[(576 + j) * 256 + n]; }
}

// ---------------------------------------------------------------------------
// transpose attn (B,HW,S) -> attnT (B,S,HW) via LDS tiles; fully coalesced.
// ---------------------------------------------------------------------------
__global__ void transpose_attn_kernel(const float* __restrict__ attn,
                                      float* __restrict__ attnT)
{
  __shared__ float t[64][65];
  int b = blockIdx.x >> 6, j0 = (blockIdx.x & 63) << 6;
  for (int idx = threadIdx.x; idx < 4096; idx += 256) {
    int r = idx >> 6, c = idx & 63;
    t[r][c] = attn[((size_t)(b * 4096 + j0 + r)) * 64 + c];
  }
  __syncthreads();
  for (int idx = threadIdx.x; idx < 4096; idx += 256) {
    int s = idx >> 6, r = idx & 63;
    attnT[((size_t)(b * 64 + s)) * 4096 + j0 + r] = t[r][s];
  }
}

// ---------------------------------------------------------------------------
// segmax: argmax over S (first occurrence) per (b, pixel)
// ---------------------------------------------------------------------------
__global__ void segmax_kernel(const float* __restrict__ attn, int* __restrict__ segm)
{
  int t = blockIdx.x * 256 + threadIdx.x;
  if (t >= B_ * HW_) return;
  const float* a = attn + (size_t)t * S_;
  float best = a[0]; int bi = 0;
  for (int s = 1; s < S_; ++s) { float v = a[s]; if (v > best) { best = v; bi = s; } }
  segm[t] = bi;
}

// ---------------------------------------------------------------------------
// topk: per (b,s) block, top-4 over 4096 pixels, reading coalesced attnT.
// Tie semantics: sorted descending, equal values -> lower index first.
// ---------------------------------------------------------------------------
__global__ void topk_kernel(const float* __restrict__ attnT,
                            int* __restrict__ refc, float* __restrict__ wprob)
{
  int bid = blockIdx.x;                 // b*64 + s
  int tid = threadIdx.x;
  __shared__ float sv[256]; __shared__ int si[256];
  __shared__ float cvs[4]; __shared__ int cis[4];

  const float* col = attnT + (size_t)bid * 4096;
  float tv[4] = { -INFINITY, -INFINITY, -INFINITY, -INFINITY };
  int   ti[4] = { 0x7fffffff, 0x7fffffff, 0x7fffffff, 0x7fffffff };
  for (int j = tid; j < HW_; j += 256) {
    float v = col[j];
    if (v > tv[3]) {                    // equal value: existing (lower idx) wins
      tv[3] = v; ti[3] = j;
      #pragma unroll
      for (int x = 3; x > 0; --x) {
        if (tv[x] > tv[x-1] || (tv[x] == tv[x-1] && ti[x] < ti[x-1])) {
          float fv = tv[x]; tv[x] = tv[x-1]; tv[x-1] = fv;
          int   fi = ti[x]; ti[x] = ti[x-1]; ti[x-1] = fi;
        }
      }
    }
  }
  int ptr = 0;
  for (int r = 0; r < 4; ++r) {
    sv[tid] = (ptr < 4) ? tv[ptr] : -INFINITY;
    si[tid] = (ptr < 4) ? ti[ptr] : 0x7fffffff;
    __syncthreads();
    for (int o = 128; o; o >>= 1) {
      if (tid < o) {
        float v2 = sv[tid + o]; int i2 = si[tid + o];
        if (v2 > sv[tid] || (v2 == sv[tid] && i2 < si[tid])) { sv[tid] = v2; si[tid] = i2; }
      }
      __syncthreads();
    }
    if (tid == 0) { cvs[r] = sv[0]; cis[r] = si[0]; }
    __syncthreads();
    if (ptr < 4 && ti[ptr] == cis[r]) ptr++;
    __syncthreads();
  }
  if (tid == 0) {
    float ssum = cvs[0] + cvs[1] + cvs[2] + cvs[3];
    for (int k = 0; k < 4; ++k) { refc[bid*4 + k] = cis[k]; wprob[bid*4 + k] = cvs[k] / ssum; }
  }
}

// ---------------------------------------------------------------------------
// meta: per query build 8 MLP-row descriptors {src pixel-row, tail t[4], weight}
// ---------------------------------------------------------------------------
__global__ void meta_kernel(const float* __restrict__ coord, const float* __restrict__ cell,
                            const int* __restrict__ segm, const int* __restrict__ refc,
                            const float* __restrict__ wprob,
                            int* __restrict__ msrc, float4* __restrict__ mt,
                            float* __restrict__ mwgt)
{
  int q = blockIdx.x * 256 + threadIdx.x;
  if (q >= NQ_) return;
  int b = q >> 13;
  float c0 = coord[2*q], c1 = coord[2*q + 1];
  float rc0 = cell[2*q] * 64.0f, rc1 = cell[2*q + 1] * 64.0f;   // rel_cell

  // ---- attention branch ----
  float pf0 = (c0 + 1.0f) / 2.0f * 64.0f;
  float pf1 = (c1 + 1.0f) / 2.0f * 64.0f;
  int pc0 = (int)pf0, pc1 = (int)pf1;           // trunc (non-negative)
  pc0 = min(max(pc0, 0), 4095); pc1 = min(max(pc1, 0), 4095);
  int pc1d = pc0 * 64 + pc1;
  int sg = segm[b * 4096 + min(pc1d, 4095)];
  int base = (b * 64 + sg) * 4;
  #pragma unroll
  for (int k = 0; k < 4; ++k) {
    int rc = refc[base + k];
    int rrc = rc - pc1d;
    float rel0 = (float)(rrc >> 6) * 0.015625f;   // floor-div by 64 then /64
    float rel1 = (float)(rrc & 63) * 0.015625f;
    int r = q * 8 + k;
    msrc[r] = rc;                                  // batch-0 gather (faithful)
    mt[r] = make_float4(rel0, rel1, rc0, rc1);
    mwgt[r] = 0.5f * wprob[base + k];
  }

  // ---- local ensemble branch ----
  const float sg0[4] = { -1.f, -1.f, 1.f, 1.f };
  const float sg1[4] = { -1.f,  1.f, -1.f, 1.f };
  float area[4], rr0[4], rr1[4]; int srcs[4];
  #pragma unroll
  for (int t = 0; t < 4; ++t) {
    float o0 = sg0[t] * 0.015625f + 1e-6f;
    float o1 = sg1[t] * 0.015625f + 1e-6f;
    float cc0 = fminf(fmaxf(c0 + o0, -1.0f + 1e-6f), 1.0f - 1e-6f);
    float cc1 = fminf(fmaxf(c1 + o1, -1.0f + 1e-6f), 1.0f - 1e-6f);
    float vy = ((cc0 + 1.0f) * 64.0f - 1.0f) / 2.0f;
    float vx = ((cc1 + 1.0f) * 64.0f - 1.0f) / 2.0f;
    float fy = fminf(fmaxf(rintf(vy), 0.0f), 63.0f);   // rint (RNE) then clip
    float fx = fminf(fmaxf(rintf(vx), 0.0f), 63.0f);
    int iy = (int)fy, ix = (int)fx;
    srcs[t] = b * 4096 + iy * 64 + ix;
    float qc0 = -1.0f + (2.0f * (float)iy + 1.0f) / 64.0f;
    float qc1 = -1.0f + (2.0f * (float)ix + 1.0f) / 64.0f;
    float r0 = (c0 - qc0) * 64.0f;
    float r1 = (c1 - qc1) * 64.0f;
    rr0[t] = r0; rr1[t] = r1;
    area[t] = fabsf(r0 * r1) + 1e-9f;
  }
  float tot = area[0] + area[1] + area[2] + area[3];
  #pragma unroll
  for (int t = 0; t < 4; ++t) {
    int r = q * 8 + 4 + t;
    msrc[r] = srcs[t];
    mt[r] = make_float4(rr0[t], rr1[t], rc0, rc1);
    mwgt[r] = 0.5f * area[3 - t] / tot;            // wts = area[::-1]/tot
  }
}

// ---------------------------------------------------------------------------
// P0 GEMM (f16 MFMA): P0[b*hw+p][n] = sum_{k<576} unfold(feat)[p][k] * w0[k][n]
// ---------------------------------------------------------------------------
__launch_bounds__(256, 2)
__global__ void p0_kernel(const _Float16* __restrict__ featT,
                          const _Float16* __restrict__ w0rT,
                          float* __restrict__ P0)
{
  int blk = blockIdx.x;                 // b*64 + y
  int b = blk >> 6, y = blk & 63;
  int tid = threadIdx.x;
  int wave = tid >> 6, lane = tid & 63, quad = lane >> 4, l16 = lane & 15;
  int colbase = wave * 64;

  f32x4 acc[4][4];
  #pragma unroll
  for (int i = 0; i < 4; i++)
    #pragma unroll
    for (int j = 0; j < 4; j++) { f32x4 z = {0.f,0.f,0.f,0.f}; acc[i][j] = z; }
  h8 zero8 = {0,0,0,0,0,0,0,0};

  for (int ks = 0; ks < 18; ++ks) {     // K = 576 = 18*32
    int k0 = ks * 32 + quad * 8;
    int kk = k0 >> 6, cc = k0 & 63;
    int di = kk / 3 - 1, dj = kk - (kk / 3) * 3 - 1;
    int yy = y + di;
    h8 afr[4];
    #pragma unroll
    for (int rb = 0; rb < 4; rb++) {
      int x = rb * 16 + l16;
      int xx = x + dj;
      if ((unsigned)yy < 64u && (unsigned)xx < 64u)
        afr[rb] = *(const h8*)(featT + ((((size_t)b * 64 + yy) * 64 + xx) * 64 + cc));
      else
        afr[rb] = zero8;
    }
    h8 bfr[4];
    #pragma unroll
    for (int cb = 0; cb < 4; cb++) {
      int n = colbase + cb * 16 + l16;
      bfr[cb] = *(const h8*)(w0rT + (size_t)n * 576 + k0);
    }
    #pragma unroll
    for (int rb = 0; rb < 4; rb++)
      #pragma unroll
      for (int cb = 0; cb < 4; cb++)
        acc[rb][cb] = __builtin_amdgcn_mfma_f32_16x16x32_f16(afr[rb], bfr[cb], acc[rb][cb], 0, 0, 0);
  }
  int pixbase = blk * 64;
  #pragma unroll
  for (int rb = 0; rb < 4; rb++)
    #pragma unroll
    for (int cb = 0; cb < 4; cb++)
      #pragma unroll
      for (int i = 0; i < 4; i++) {
        int m = rb * 16 + quad * 4 + i;
        int n = colbase + cb * 16 + l16;
        P0[((size_t)pixbase + m) * 256 + n] = acc[rb][cb][i];
      }
}

// ---------------------------------------------------------------------------
// Fused MLP trunk (f16 MFMA): seed -> 3x (256x256 MFMA + relu, SINGLE LDS
// buffer, in-place update) -> 256->3 epilogue -> 8-row weighted reduce -> f32.
// 64 rows / block, 4 waves x 64 cols. LDS 38.9 KB => 4 blocks/CU.
// In-place is safe: all waves finish reading hS before the post-MFMA barrier;
// writes happen after it; next reads after the second barrier.
// ---------------------------------------------------------------------------
__launch_bounds__(256, 4)
__global__ void trunk_kernel(const float* __restrict__ P0,
                             const int* __restrict__ msrc,
                             const float4* __restrict__ mt,
                             const float* __restrict__ mwgt,
                             const float* __restrict__ w0tail,
                             const float* __restrict__ b0,
                             const _Float16* __restrict__ wT123,
                             const float* __restrict__ b1,
                             const float* __restrict__ b2,
                             const float* __restrict__ b3,
                             const float* __restrict__ w4T,
                             const float* __restrict__ b4,
                             float* __restrict__ out)
{
  __shared__ _Float16 hS[64][264];      // +8 pad; 16B-aligned rows (528 B)
  __shared__ float part_s[64][4][4];
  __shared__ float red[64][4];

  int tid = threadIdx.x;
  int rowbase = blockIdx.x * 64;

  // ---- seed: h0 = relu(P0[src] + t . w0tail + b0), packed 8B LDS writes ----
  {
    int cg = tid & 63;
    float4 wt0 = ((const float4*)w0tail)[cg];
    float4 wt1 = ((const float4*)w0tail)[64 + cg];
    float4 wt2 = ((const float4*)w0tail)[128 + cg];
    float4 wt3 = ((const float4*)w0tail)[192 + cg];
    float4 bb  = ((const float4*)b0)[cg];
    for (int rr = tid >> 6; rr < 64; rr += 4) {
      int r = rowbase + rr;
      int src = msrc[r];
      float4 t = mt[r];
      float4 p = ((const float4*)(P0 + (size_t)src * 256))[cg];
      h4 v;
      v[0] = (_Float16)fmaxf(p.x + t.x*wt0.x + t.y*wt1.x + t.z*wt2.x + t.w*wt3.x + bb.x, 0.0f);
      v[1] = (_Float16)fmaxf(p.y + t.x*wt0.y + t.y*wt1.y + t.z*wt2.y + t.w*wt3.y + bb.y, 0.0f);
      v[2] = (_Float16)fmaxf(p.z + t.x*wt0.z + t.y*wt1.z + t.z*wt2.z + t.w*wt3.z + bb.z, 0.0f);
      v[3] = (_Float16)fmaxf(p.w + t.x*wt0.w + t.y*wt1.w + t.z*wt2.w + t.w*wt3.w + bb.w, 0.0f);
      *(h4*)(&hS[rr][cg * 4]) = v;
    }
  }
  __syncthreads();

  int wave = tid >> 6, lane = tid & 63, quad = lane >> 4, l16 = lane & 15;

  #pragma unroll 1
  for (int l = 0; l < 3; ++l) {
    const _Float16* wT = wT123 + (size_t)l * 65536;
    const float* bia = (l == 0) ? b1 : (l == 1) ? b2 : b3;
    f32x4 acc[4][4];
    #pragma unroll
    for (int i = 0; i < 4; i++)
      #pragma unroll
      for (int j = 0; j < 4; j++) { f32x4 z = {0.f,0.f,0.f,0.f}; acc[i][j] = z; }
    #pragma unroll
    for (int ks = 0; ks < 8; ++ks) {
      int k0 = ks * 32 + quad * 8;
      h8 afr[4], bfr[4];
      #pragma unroll
      for (int rb = 0; rb < 4; rb++)
        afr[rb] = *(const h8*)(&hS[rb * 16 + l16][k0]);
      #pragma unroll
      for (int cb = 0; cb < 4; cb++) {
        int n = wave * 64 + cb * 16 + l16;
        bfr[cb] = *(const h8*)(wT + (size_t)n * 256 + k0);
      }
      #pragma unroll
      for (int rb = 0; rb < 4; rb++)
        #pragma unroll
        for (int cb = 0; cb < 4; cb++)
          acc[rb][cb] = __builtin_amdgcn_mfma_f32_16x16x32_f16(afr[rb], bfr[cb], acc[rb][cb], 0, 0, 0);
    }
    __syncthreads();                    // all reads of hS complete
    #pragma unroll
    for (int rb = 0; rb < 4; rb++)
      #pragma unroll
      for (int cb = 0; cb < 4; cb++) {
        int n = wave * 64 + cb * 16 + l16;
        float bv = bia[n];
        #pragma unroll
        for (int i = 0; i < 4; i++) {
          int m = rb * 16 + quad * 4 + i;
          hS[m][n] = (_Float16)fmaxf(acc[rb][cb][i] + bv, 0.0f);   // in-place
        }
      }
    __syncthreads();                    // writes visible before next reads
  }

  // ---- epilogue: y = h3 @ w4 + b4, weight, reduce 8 rows/query ----
  {
    int row = tid >> 2, part = tid & 3;
    const _Float16* hr = &hS[row][part * 64];
    float s0 = 0.f, s1 = 0.f, s2 = 0.f;
    #pragma unroll
    for (int c8 = 0; c8 < 64; c8 += 8) {
      h8 hv = *(const h8*)(hr + c8);
      #pragma unroll
      for (int u = 0; u < 8; ++u) {
        float h = (float)hv[u];
        int c = part * 64 + c8 + u;
        s0 += h * w4T[c];
        s1 += h * w4T[256 + c];
        s2 += h * w4T[512 + c];
      }
    }
    part_s[row][part][0] = s0; part_s[row][part][1] = s1; part_s[row][part][2] = s2;
  }
  __syncthreads();
  if (tid < 64) {
    float wgt = mwgt[rowbase + tid];
    red[tid][0] = (part_s[tid][0][0] + part_s[tid][1][0] + part_s[tid][2][0] + part_s[tid][3][0] + b4[0]) * wgt;
    red[tid][1] = (part_s[tid][0][1] + part_s[tid][1][1] + part_s[tid][2][1] + part_s[tid][3][1] + b4[1]) * wgt;
    red[tid][2] = (part_s[tid][0][2] + part_s[tid][1][2] + part_s[tid][2][2] + part_s[tid][3][2] + b4[2]) * wgt;
  }
  __syncthreads();
  if (tid < 8) {
    int q = (rowbase >> 3) + tid;       // global query index b*N+n
    float o0 = 0.f, o1 = 0.f, o2 = 0.f;
    #pragma unroll
    for (int j = 0; j < 8; j++) {
      o0 += red[tid * 8 + j][0];
      o1 += red[tid * 8 + j][1];
      o2 += red[tid * 8 + j][2];
    }
    out[q * 3 + 0] = o0;
    out[q * 3 + 1] = o1;
    out[q * 3 + 2] = o2;
  }
}

// ---------------------------------------------------------------------------
extern "C" void kernel_launch(void* const* d_in, const int* in_sizes, int n_in,
                              void* d_out, int out_size, void* d_ws, size_t ws_size,
                              hipStream_t stream)
{
  const float* feat  = (const float*)d_in[0];
  const float* attn  = (const float*)d_in[1];
  const float* coord = (const float*)d_in[2];
  const float* cell  = (const float*)d_in[3];
  const float* w0 = (const float*)d_in[4];
  const float* b0 = (const float*)d_in[5];
  const float* w1 = (const float*)d_in[6];
  const float* b1 = (const float*)d_in[7];
  const float* w2 = (const float*)d_in[8];
  const float* b2 = (const float*)d_in[9];
  const float* w3 = (const float*)d_in[10];
  const float* b3 = (const float*)d_in[11];
  const float* w4 = (const float*)d_in[12];
  const float* b4 = (const float*)d_in[13];
  float* out = (float*)d_out;           // reference output dtype = float32

  char* ws = (char*)d_ws;
  size_t off = 0;
  auto alloc = [&](size_t bytes) -> char* {
    char* p = ws + off;
    off += (bytes + 255) & ~(size_t)255;
    return p;
  };
  _Float16* featT = (_Float16*)alloc((size_t)B_ * H_ * W_ * D_ * 2);  //  2.10 MB
  _Float16* w0rT  = (_Float16*)alloc((size_t)256 * 576 * 2);          //  0.29 MB
  _Float16* wT123 = (_Float16*)alloc((size_t)3 * 256 * 256 * 2);      //  0.39 MB
  float*  w4T   = (float*)alloc((size_t)3 * 256 * 4);
  float*  w0tl  = (float*)alloc((size_t)4 * 256 * 4);
  float*  attnT = (float*)alloc((size_t)B_ * S_ * HW_ * 4);           //  4.2 MB
  int*    segm  = (int*)alloc((size_t)B_ * HW_ * 4);                  //  64 KB
  int*    refc  = (int*)alloc((size_t)B_ * S_ * K_ * 4);
  float*  wprob = (float*)alloc((size_t)B_ * S_ * K_ * 4);
  float*  P0    = (float*)alloc((size_t)B_ * HW_ * 256 * 4);          // 16.8 MB
  int*    msrc  = (int*)alloc((size_t)ROWS_ * 4);                     //  1.0 MB
  float4* mtb   = (float4*)alloc((size_t)ROWS_ * 16);                 //  4.2 MB
  float*  mwgt  = (float*)alloc((size_t)ROWS_ * 4);                   //  1.0 MB
  (void)in_sizes; (void)n_in; (void)out_size; (void)ws_size;          // ~31 MB total

  prep_kernel<<<(1394432 + 255) / 256, 256, 0, stream>>>(feat, w0, w1, w2, w3, w4,
                                                         featT, w0rT, wT123, w4T, w0tl);
  transpose_attn_kernel<<<256, 256, 0, stream>>>(attn, attnT);
  segmax_kernel<<<64, 256, 0, stream>>>(attn, segm);
  topk_kernel<<<256, 256, 0, stream>>>(attnT, refc, wprob);
  meta_kernel<<<128, 256, 0, stream>>>(coord, cell, segm, refc, wprob, msrc, mtb, mwgt);
  p0_kernel<<<256, 256, 0, stream>>>(featT, w0rT, P0);
  trunk_kernel<<<4096, 256, 0, stream>>>(P0, msrc, mtb, mwgt, w0tl, b0, wT123,
                                         b1, b2, b3, w4T, b4, out);
}

// Round 7
// 372.576 us; speedup vs baseline: 1.3024x; 1.2463x over previous
//
#include <hip/hip_runtime.h>
#include <hip/hip_bf16.h>
#include <math.h>
#include <stdint.h>

#define B_ 4
#define D_ 64
#define H_ 64
#define W_ 64
#define S_ 64
#define N_ 8192
#define K_ 4
#define HID_ 256
#define HW_ 4096
#define NQ_ (B_*N_)        // 32768 queries
#define ROWS_ (NQ_*8)      // 262144 MLP rows (4 attn + 4 local per query)

typedef _Float16 h8   __attribute__((ext_vector_type(8)));
typedef _Float16 h4   __attribute__((ext_vector_type(4)));
typedef float    f32x4 __attribute__((ext_vector_type(4)));

// ---------------------------------------------------------------------------
// transpose feat (B,D,H,W) -> featT[b][y][x][c] (f16) via LDS tiles.
// One block per (b,y): reads coalesced along x, writes coalesced along c.
// ---------------------------------------------------------------------------
__global__ void transpose_feat_kernel(const float* __restrict__ feat,
                                      _Float16* __restrict__ featT)
{
  __shared__ float t[64][65];
  int b = blockIdx.x >> 6, y = blockIdx.x & 63;
  int tid = threadIdx.x;
  // read: 4 c-rows x 64 x per pass
  for (int p = 0; p < 16; ++p) {
    int c = p * 4 + (tid >> 6), x = tid & 63;
    t[c][x] = feat[(((size_t)b * 64 + c) << 12) + (y << 6) + x];
  }
  __syncthreads();
  // write: 4 x-rows x 64 c per pass, featT linear in c
  for (int p = 0; p < 16; ++p) {
    int x = p * 4 + (tid >> 6), c = tid & 63;
    featT[((((size_t)b * 64 + y) * 64 + x) << 6) + c] = (_Float16)t[c][x];
  }
}

// ---------------------------------------------------------------------------
// prep: fragment-linear weights.
// w0F[g][ks18][cb][lane][8]  : n=g*64+cb*16+(lane&15), k=ks*32+(lane>>4)*8+j,
//                              k=kk*64+cc (reordered) <- w0[(cc*9+kk)][n]
// wF123[l][g][ks8][cb][lane][8]: n as above, k=ks*32+(lane>>4)*8+j <- w_l[k][n]
// w4T[j][c] (f32), w0tail[j][n] (f32)
// ---------------------------------------------------------------------------
__global__ void prep_kernel(const float* __restrict__ w0,
                            const float* __restrict__ w1,
                            const float* __restrict__ w2,
                            const float* __restrict__ w3,
                            const float* __restrict__ w4,
                            _Float16* __restrict__ w0F,
                            _Float16* __restrict__ wF123,
                            float* __restrict__ w4T,
                            float* __restrict__ w0tail)
{
  int i = blockIdx.x * 256 + threadIdx.x;
  if (i < 147456) {                        // w0F
    int g = i / 36864, rem = i - g * 36864;
    int ks = rem >> 11, rem2 = rem & 2047;
    int cb = rem2 >> 9, e = rem2 & 511;
    int lane = e >> 3, j = e & 7;
    int n = g * 64 + cb * 16 + (lane & 15);
    int k = ks * 32 + (lane >> 4) * 8 + j;         // reordered k = kk*64+cc
    int kk = k >> 6, cc = k & 63;
    w0F[i] = (_Float16)w0[(cc * 9 + kk) * 256 + n];
    return;
  }
  i -= 147456;
  if (i < 196608) {                        // wF123
    int l = i >> 16, rem = i & 65535;
    int g = rem >> 14, rem2 = rem & 16383;
    int ks = rem2 >> 11, rem3 = rem2 & 2047;
    int cb = rem3 >> 9, e = rem3 & 511;
    int lane = e >> 3, j = e & 7;
    int n = g * 64 + cb * 16 + (lane & 15);
    int k = ks * 32 + (lane >> 4) * 8 + j;
    const float* w = (l == 0) ? w1 : (l == 1) ? w2 : w3;
    wF123[i] = (_Float16)w[k * 256 + n];
    return;
  }
  i -= 196608;
  if (i < 768) { int j = i / 256, c = i - j * 256; w4T[i] = w4[c * 3 + j]; return; }
  i -= 768;
  if (i < 1024) { int j = i >> 8, n = i & 255; w0tail[i] = w0[(576 + j) * 256 + n]; }
}

// ---------------------------------------------------------------------------
// transpose attn (B,HW,S) -> attnT (B,S,HW) via LDS tiles; fully coalesced.
// ---------------------------------------------------------------------------
__global__ void transpose_attn_kernel(const float* __restrict__ attn,
                                      float* __restrict__ attnT)
{
  __shared__ float t[64][65];
  int b = blockIdx.x >> 6, j0 = (blockIdx.x & 63) << 6;
  for (int idx = threadIdx.x; idx < 4096; idx += 256) {
    int r = idx >> 6, c = idx & 63;
    t[r][c] = attn[((size_t)(b * 4096 + j0 + r)) * 64 + c];
  }
  __syncthreads();
  for (int idx = threadIdx.x; idx < 4096; idx += 256) {
    int s = idx >> 6, r = idx & 63;
    attnT[((size_t)(b * 64 + s)) * 4096 + j0 + r] = t[r][s];
  }
}

// ---------------------------------------------------------------------------
// segmax: argmax over S (first occurrence) per (b, pixel)
// ---------------------------------------------------------------------------
__global__ void segmax_kernel(const float* __restrict__ attn, int* __restrict__ segm)
{
  int t = blockIdx.x * 256 + threadIdx.x;
  if (t >= B_ * HW_) return;
  const float* a = attn + (size_t)t * S_;
  float best = a[0]; int bi = 0;
  for (int s = 1; s < S_; ++s) { float v = a[s]; if (v > best) { best = v; bi = s; } }
  segm[t] = bi;
}

// ---------------------------------------------------------------------------
// topk: per (b,s) block, top-4 over 4096 pixels, reading coalesced attnT.
// ---------------------------------------------------------------------------
__global__ void topk_kernel(const float* __restrict__ attnT,
                            int* __restrict__ refc, float* __restrict__ wprob)
{
  int bid = blockIdx.x;                 // b*64 + s
  int tid = threadIdx.x;
  __shared__ float sv[256]; __shared__ int si[256];
  __shared__ float cvs[4]; __shared__ int cis[4];

  const float* col = attnT + (size_t)bid * 4096;
  float tv[4] = { -INFINITY, -INFINITY, -INFINITY, -INFINITY };
  int   ti[4] = { 0x7fffffff, 0x7fffffff, 0x7fffffff, 0x7fffffff };
  for (int j = tid; j < HW_; j += 256) {
    float v = col[j];
    if (v > tv[3]) {                    // equal value: existing (lower idx) wins
      tv[3] = v; ti[3] = j;
      #pragma unroll
      for (int x = 3; x > 0; --x) {
        if (tv[x] > tv[x-1] || (tv[x] == tv[x-1] && ti[x] < ti[x-1])) {
          float fv = tv[x]; tv[x] = tv[x-1]; tv[x-1] = fv;
          int   fi = ti[x]; ti[x] = ti[x-1]; ti[x-1] = fi;
        }
      }
    }
  }
  int ptr = 0;
  for (int r = 0; r < 4; ++r) {
    sv[tid] = (ptr < 4) ? tv[ptr] : -INFINITY;
    si[tid] = (ptr < 4) ? ti[ptr] : 0x7fffffff;
    __syncthreads();
    for (int o = 128; o; o >>= 1) {
      if (tid < o) {
        float v2 = sv[tid + o]; int i2 = si[tid + o];
        if (v2 > sv[tid] || (v2 == sv[tid] && i2 < si[tid])) { sv[tid] = v2; si[tid] = i2; }
      }
      __syncthreads();
    }
    if (tid == 0) { cvs[r] = sv[0]; cis[r] = si[0]; }
    __syncthreads();
    if (ptr < 4 && ti[ptr] == cis[r]) ptr++;
    __syncthreads();
  }
  if (tid == 0) {
    float ssum = cvs[0] + cvs[1] + cvs[2] + cvs[3];
    for (int k = 0; k < 4; ++k) { refc[bid*4 + k] = cis[k]; wprob[bid*4 + k] = cvs[k] / ssum; }
  }
}

// ---------------------------------------------------------------------------
// meta: per query build 8 MLP-row descriptors {src pixel-row, tail t[4], weight}
// ---------------------------------------------------------------------------
__global__ void meta_kernel(const float* __restrict__ coord, const float* __restrict__ cell,
                            const int* __restrict__ segm, const int* __restrict__ refc,
                            const float* __restrict__ wprob,
                            int* __restrict__ msrc, float4* __restrict__ mt,
                            float* __restrict__ mwgt)
{
  int q = blockIdx.x * 256 + threadIdx.x;
  if (q >= NQ_) return;
  int b = q >> 13;
  float c0 = coord[2*q], c1 = coord[2*q + 1];
  float rc0 = cell[2*q] * 64.0f, rc1 = cell[2*q + 1] * 64.0f;   // rel_cell

  // ---- attention branch ----
  float pf0 = (c0 + 1.0f) / 2.0f * 64.0f;
  float pf1 = (c1 + 1.0f) / 2.0f * 64.0f;
  int pc0 = (int)pf0, pc1 = (int)pf1;           // trunc (non-negative)
  pc0 = min(max(pc0, 0), 4095); pc1 = min(max(pc1, 0), 4095);
  int pc1d = pc0 * 64 + pc1;
  int sg = segm[b * 4096 + min(pc1d, 4095)];
  int base = (b * 64 + sg) * 4;
  #pragma unroll
  for (int k = 0; k < 4; ++k) {
    int rc = refc[base + k];
    int rrc = rc - pc1d;
    float rel0 = (float)(rrc >> 6) * 0.015625f;   // floor-div by 64 then /64
    float rel1 = (float)(rrc & 63) * 0.015625f;
    int r = q * 8 + k;
    msrc[r] = rc;                                  // batch-0 gather (faithful)
    mt[r] = make_float4(rel0, rel1, rc0, rc1);
    mwgt[r] = 0.5f * wprob[base + k];
  }

  // ---- local ensemble branch ----
  const float sg0[4] = { -1.f, -1.f, 1.f, 1.f };
  const float sg1[4] = { -1.f,  1.f, -1.f, 1.f };
  float area[4], rr0[4], rr1[4]; int srcs[4];
  #pragma unroll
  for (int t = 0; t < 4; ++t) {
    float o0 = sg0[t] * 0.015625f + 1e-6f;
    float o1 = sg1[t] * 0.015625f + 1e-6f;
    float cc0 = fminf(fmaxf(c0 + o0, -1.0f + 1e-6f), 1.0f - 1e-6f);
    float cc1 = fminf(fmaxf(c1 + o1, -1.0f + 1e-6f), 1.0f - 1e-6f);
    float vy = ((cc0 + 1.0f) * 64.0f - 1.0f) / 2.0f;
    float vx = ((cc1 + 1.0f) * 64.0f - 1.0f) / 2.0f;
    float fy = fminf(fmaxf(rintf(vy), 0.0f), 63.0f);   // rint (RNE) then clip
    float fx = fminf(fmaxf(rintf(vx), 0.0f), 63.0f);
    int iy = (int)fy, ix = (int)fx;
    srcs[t] = b * 4096 + iy * 64 + ix;
    float qc0 = -1.0f + (2.0f * (float)iy + 1.0f) / 64.0f;
    float qc1 = -1.0f + (2.0f * (float)ix + 1.0f) / 64.0f;
    float r0 = (c0 - qc0) * 64.0f;
    float r1 = (c1 - qc1) * 64.0f;
    rr0[t] = r0; rr1[t] = r1;
    area[t] = fabsf(r0 * r1) + 1e-9f;
  }
  float tot = area[0] + area[1] + area[2] + area[3];
  #pragma unroll
  for (int t = 0; t < 4; ++t) {
    int r = q * 8 + 4 + t;
    msrc[r] = srcs[t];
    mt[r] = make_float4(rr0[t], rr1[t], rc0, rc1);
    mwgt[r] = 0.5f * area[3 - t] / tot;            // wts = area[::-1]/tot
  }
}

// ---------------------------------------------------------------------------
// P0 GEMM (f16 MFMA): 1024 blocks = (b, y, quarter-row); 16 pixels x 256 cols.
// B-frags from fragment-linear w0F (contiguous 1 KB per load).
// ---------------------------------------------------------------------------
__launch_bounds__(256, 4)
__global__ void p0_kernel(const _Float16* __restrict__ featT,
                          const _Float16* __restrict__ w0F,
                          float* __restrict__ P0)
{
  int blk = blockIdx.x;                 // b*256 + y*4 + qr
  int b = blk >> 8, y = (blk >> 2) & 63, qr = blk & 3;
  int tid = threadIdx.x;
  int wave = tid >> 6, lane = tid & 63, quad = lane >> 4, l16 = lane & 15;

  f32x4 acc[4];
  #pragma unroll
  for (int j = 0; j < 4; j++) { f32x4 z = {0.f,0.f,0.f,0.f}; acc[j] = z; }
  h8 zero8 = {0,0,0,0,0,0,0,0};

  #pragma unroll
  for (int ks = 0; ks < 18; ++ks) {     // K = 576 = 18*32
    int k0 = ks * 32 + quad * 8;
    int kk = k0 >> 6, cc = k0 & 63;
    int di = kk / 3 - 1, dj = kk - (kk / 3) * 3 - 1;
    int yy = y + di;
    int xx = qr * 16 + l16 + dj;
    h8 afr;
    if ((unsigned)yy < 64u && (unsigned)xx < 64u)
      afr = *(const h8*)(featT + ((((size_t)b * 64 + yy) * 64 + xx) << 6) + cc);
    else
      afr = zero8;
    #pragma unroll
    for (int cb = 0; cb < 4; cb++) {
      h8 bfr = *(const h8*)(w0F + ((((size_t)wave * 18 + ks) * 4 + cb) << 9) + lane * 8);
      acc[cb] = __builtin_amdgcn_mfma_f32_16x16x32_f16(afr, bfr, acc[cb], 0, 0, 0);
    }
  }
  int pixbase = (b * 4096 + y * 64 + qr * 16);
  #pragma unroll
  for (int cb = 0; cb < 4; cb++)
    #pragma unroll
    for (int i = 0; i < 4; i++) {
      int m = quad * 4 + i;
      int n = wave * 64 + cb * 16 + l16;
      P0[((size_t)(pixbase + m) << 8) + n] = acc[cb][i];
    }
}

// ---------------------------------------------------------------------------
// Fused MLP trunk (f16 MFMA): seed -> 3x (256x256 MFMA + relu, single LDS
// buffer, in-place) -> 256->3 epilogue -> 8-row weighted reduce -> f32.
// 64 rows/block, 4 waves x 64 cols. B-frags from fragment-linear wF123.
// launch_bounds(256,3): ~170 VGPR so the K-loop's loads pipeline deeply.
// ---------------------------------------------------------------------------
__launch_bounds__(256, 3)
__global__ void trunk_kernel(const float* __restrict__ P0,
                             const int* __restrict__ msrc,
                             const float4* __restrict__ mt,
                             const float* __restrict__ mwgt,
                             const float* __restrict__ w0tail,
                             const float* __restrict__ b0,
                             const _Float16* __restrict__ wF123,
                             const float* __restrict__ b1,
                             const float* __restrict__ b2,
                             const float* __restrict__ b3,
                             const float* __restrict__ w4T,
                             const float* __restrict__ b4,
                             float* __restrict__ out)
{
  __shared__ _Float16 hS[64][264];      // +8 pad; 16B-aligned rows (528 B)
  __shared__ float part_s[64][4][4];
  __shared__ float red[64][4];

  int tid = threadIdx.x;
  int rowbase = blockIdx.x * 64;

  // ---- seed: h0 = relu(P0[src] + t . w0tail + b0), packed 8B LDS writes ----
  {
    int cg = tid & 63;
    float4 wt0 = ((const float4*)w0tail)[cg];
    float4 wt1 = ((const float4*)w0tail)[64 + cg];
    float4 wt2 = ((const float4*)w0tail)[128 + cg];
    float4 wt3 = ((const float4*)w0tail)[192 + cg];
    float4 bb  = ((const float4*)b0)[cg];
    for (int rr = tid >> 6; rr < 64; rr += 4) {
      int r = rowbase + rr;
      int src = msrc[r];
      float4 t = mt[r];
      float4 p = ((const float4*)(P0 + ((size_t)src << 8)))[cg];
      h4 v;
      v[0] = (_Float16)fmaxf(p.x + t.x*wt0.x + t.y*wt1.x + t.z*wt2.x + t.w*wt3.x + bb.x, 0.0f);
      v[1] = (_Float16)fmaxf(p.y + t.x*wt0.y + t.y*wt1.y + t.z*wt2.y + t.w*wt3.y + bb.y, 0.0f);
      v[2] = (_Float16)fmaxf(p.z + t.x*wt0.z + t.y*wt1.z + t.z*wt2.z + t.w*wt3.z + bb.z, 0.0f);
      v[3] = (_Float16)fmaxf(p.w + t.x*wt0.w + t.y*wt1.w + t.z*wt2.w + t.w*wt3.w + bb.w, 0.0f);
      *(h4*)(&hS[rr][cg * 4]) = v;
    }
  }
  __syncthreads();

  int wave = tid >> 6, lane = tid & 63, quad = lane >> 4, l16 = lane & 15;

  #pragma unroll 1
  for (int l = 0; l < 3; ++l) {
    const _Float16* wL = wF123 + (((size_t)l * 4 + wave) << 14);   // 8 ks * 4 cb * 512
    const float* bia = (l == 0) ? b1 : (l == 1) ? b2 : b3;
    f32x4 acc[4][4];
    #pragma unroll
    for (int i = 0; i < 4; i++)
      #pragma unroll
      for (int j = 0; j < 4; j++) { f32x4 z = {0.f,0.f,0.f,0.f}; acc[i][j] = z; }
    #pragma unroll
    for (int ks = 0; ks < 8; ++ks) {
      int k0 = ks * 32 + quad * 8;
      h8 afr[4], bfr[4];
      #pragma unroll
      for (int rb = 0; rb < 4; rb++)
        afr[rb] = *(const h8*)(&hS[rb * 16 + l16][k0]);
      #pragma unroll
      for (int cb = 0; cb < 4; cb++)
        bfr[cb] = *(const h8*)(wL + (((size_t)ks * 4 + cb) << 9) + lane * 8);
      #pragma unroll
      for (int rb = 0; rb < 4; rb++)
        #pragma unroll
        for (int cb = 0; cb < 4; cb++)
          acc[rb][cb] = __builtin_amdgcn_mfma_f32_16x16x32_f16(afr[rb], bfr[cb], acc[rb][cb], 0, 0, 0);
    }
    __syncthreads();                    // all reads of hS complete
    #pragma unroll
    for (int rb = 0; rb < 4; rb++)
      #pragma unroll
      for (int cb = 0; cb < 4; cb++) {
        int n = wave * 64 + cb * 16 + l16;
        float bv = bia[n];
        #pragma unroll
        for (int i = 0; i < 4; i++) {
          int m = rb * 16 + quad * 4 + i;
          hS[m][n] = (_Float16)fmaxf(acc[rb][cb][i] + bv, 0.0f);   // in-place
        }
      }
    __syncthreads();                    // writes visible before next reads
  }

  // ---- epilogue: y = h3 @ w4 + b4, weight, reduce 8 rows/query ----
  {
    int row = tid >> 2, part = tid & 3;
    const _Float16* hr = &hS[row][part * 64];
    float s0 = 0.f, s1 = 0.f, s2 = 0.f;
    #pragma unroll
    for (int c8 = 0; c8 < 64; c8 += 8) {
      h8 hv = *(const h8*)(hr + c8);
      #pragma unroll
      for (int u = 0; u < 8; ++u) {
        float h = (float)hv[u];
        int c = part * 64 + c8 + u;
        s0 += h * w4T[c];
        s1 += h * w4T[256 + c];
        s2 += h * w4T[512 + c];
      }
    }
    part_s[row][part][0] = s0; part_s[row][part][1] = s1; part_s[row][part][2] = s2;
  }
  __syncthreads();
  if (tid < 64) {
    float wgt = mwgt[rowbase + tid];
    red[tid][0] = (part_s[tid][0][0] + part_s[tid][1][0] + part_s[tid][2][0] + part_s[tid][3][0] + b4[0]) * wgt;
    red[tid][1] = (part_s[tid][0][1] + part_s[tid][1][1] + part_s[tid][2][1] + part_s[tid][3][1] + b4[1]) * wgt;
    red[tid][2] = (part_s[tid][0][2] + part_s[tid][1][2] + part_s[tid][2][2] + part_s[tid][3][2] + b4[2]) * wgt;
  }
  __syncthreads();
  if (tid < 8) {
    int q = (rowbase >> 3) + tid;       // global query index b*N+n
    float o0 = 0.f, o1 = 0.f, o2 = 0.f;
    #pragma unroll
    for (int j = 0; j < 8; j++) {
      o0 += red[tid * 8 + j][0];
      o1 += red[tid * 8 + j][1];
      o2 += red[tid * 8 + j][2];
    }
    out[q * 3 + 0] = o0;
    out[q * 3 + 1] = o1;
    out[q * 3 + 2] = o2;
  }
}

// ---------------------------------------------------------------------------
extern "C" void kernel_launch(void* const* d_in, const int* in_sizes, int n_in,
                              void* d_out, int out_size, void* d_ws, size_t ws_size,
                              hipStream_t stream)
{
  const float* feat  = (const float*)d_in[0];
  const float* attn  = (const float*)d_in[1];
  const float* coord = (const float*)d_in[2];
  const float* cell  = (const float*)d_in[3];
  const float* w0 = (const float*)d_in[4];
  const float* b0 = (const float*)d_in[5];
  const float* w1 = (const float*)d_in[6];
  const float* b1 = (const float*)d_in[7];
  const float* w2 = (const float*)d_in[8];
  const float* b2 = (const float*)d_in[9];
  const float* w3 = (const float*)d_in[10];
  const float* b3 = (const float*)d_in[11];
  const float* w4 = (const float*)d_in[12];
  const float* b4 = (const float*)d_in[13];
  float* out = (float*)d_out;           // reference output dtype = float32

  char* ws = (char*)d_ws;
  size_t off = 0;
  auto alloc = [&](size_t bytes) -> char* {
    char* p = ws + off;
    off += (bytes + 255) & ~(size_t)255;
    return p;
  };
  _Float16* featT = (_Float16*)alloc((size_t)B_ * H_ * W_ * D_ * 2);  //  2.10 MB
  _Float16* w0F   = (_Float16*)alloc((size_t)147456 * 2);             //  0.29 MB
  _Float16* wF123 = (_Float16*)alloc((size_t)196608 * 2);             //  0.39 MB
  float*  w4T   = (float*)alloc((size_t)3 * 256 * 4);
  float*  w0tl  = (float*)alloc((size_t)4 * 256 * 4);
  float*  attnT = (float*)alloc((size_t)B_ * S_ * HW_ * 4);           //  4.2 MB
  int*    segm  = (int*)alloc((size_t)B_ * HW_ * 4);                  //  64 KB
  int*    refc  = (int*)alloc((size_t)B_ * S_ * K_ * 4);
  float*  wprob = (float*)alloc((size_t)B_ * S_ * K_ * 4);
  float*  P0    = (float*)alloc((size_t)B_ * HW_ * 256 * 4);          // 16.8 MB
  int*    msrc  = (int*)alloc((size_t)ROWS_ * 4);                     //  1.0 MB
  float4* mtb   = (float4*)alloc((size_t)ROWS_ * 16);                 //  4.2 MB
  float*  mwgt  = (float*)alloc((size_t)ROWS_ * 4);                   //  1.0 MB
  (void)in_sizes; (void)n_in; (void)out_size; (void)ws_size;          // ~31 MB total

  transpose_feat_kernel<<<256, 256, 0, stream>>>(feat, featT);
  prep_kernel<<<(345856 + 255) / 256, 256, 0, stream>>>(w0, w1, w2, w3, w4,
                                                        w0F, wF123, w4T, w0tl);
  transpose_attn_kernel<<<256, 256, 0, stream>>>(attn, attnT);
  segmax_kernel<<<64, 256, 0, stream>>>(attn, segm);
  topk_kernel<<<256, 256, 0, stream>>>(attnT, refc, wprob);
  meta_kernel<<<128, 256, 0, stream>>>(coord, cell, segm, refc, wprob, msrc, mtb, mwgt);
  p0_kernel<<<1024, 256, 0, stream>>>(featT, w0F, P0);
  trunk_kernel<<<4096, 256, 0, stream>>>(P0, msrc, mtb, mwgt, w0tl, b0, wF123,
                                         b1, b2, b3, w4T, b4, out);
}

// Round 8
// 330.256 us; speedup vs baseline: 1.4693x; 1.1281x over previous
//
#include <hip/hip_runtime.h>
#include <hip/hip_bf16.h>
#include <math.h>
#include <stdint.h>

#define B_ 4
#define D_ 64
#define H_ 64
#define W_ 64
#define S_ 64
#define N_ 8192
#define K_ 4
#define HID_ 256
#define HW_ 4096
#define NQ_ (B_*N_)        // 32768 queries
#define ROWS_ (NQ_*8)      // 262144 MLP rows (4 attn + 4 local per query)

typedef _Float16 h8   __attribute__((ext_vector_type(8)));
typedef _Float16 h4   __attribute__((ext_vector_type(4)));
typedef float    f32x4 __attribute__((ext_vector_type(4)));

// ---------------------------------------------------------------------------
// fused prep: [0,256) feat transpose | [256,512) attn transpose |
// [512,1863) weight repack | [1863,1927) segmax.  One launch, no deps.
// ---------------------------------------------------------------------------
__global__ void fused_prep_kernel(const float* __restrict__ feat,
                                  const float* __restrict__ attn,
                                  const float* __restrict__ w0,
                                  const float* __restrict__ w1,
                                  const float* __restrict__ w2,
                                  const float* __restrict__ w3,
                                  const float* __restrict__ w4,
                                  _Float16* __restrict__ featT,
                                  float* __restrict__ attnT,
                                  _Float16* __restrict__ w0F,
                                  _Float16* __restrict__ wF123,
                                  float* __restrict__ w4T,
                                  float* __restrict__ w0tail,
                                  int* __restrict__ segm)
{
  __shared__ float t[64][65];
  int blk = blockIdx.x;
  int tid = threadIdx.x;

  if (blk < 256) {                       // ---- feat (B,D,H,W) -> featT[b][y][x][c]
    int b = blk >> 6, y = blk & 63;
    for (int p = 0; p < 16; ++p) {
      int c = p * 4 + (tid >> 6), x = tid & 63;
      t[c][x] = feat[(((size_t)b * 64 + c) << 12) + (y << 6) + x];
    }
    __syncthreads();
    for (int p = 0; p < 16; ++p) {
      int x = p * 4 + (tid >> 6), c = tid & 63;
      featT[((((size_t)b * 64 + y) * 64 + x) << 6) + c] = (_Float16)t[c][x];
    }
    return;
  }
  blk -= 256;
  if (blk < 256) {                       // ---- attn (B,HW,S) -> attnT (B,S,HW)
    int b = blk >> 6, j0 = (blk & 63) << 6;
    for (int idx = tid; idx < 4096; idx += 256) {
      int r = idx >> 6, c = idx & 63;
      t[r][c] = attn[((size_t)(b * 4096 + j0 + r)) * 64 + c];
    }
    __syncthreads();
    for (int idx = tid; idx < 4096; idx += 256) {
      int s = idx >> 6, r = idx & 63;
      attnT[((size_t)(b * 64 + s)) * 4096 + j0 + r] = t[r][s];
    }
    return;
  }
  blk -= 256;
  if (blk < 1351) {                      // ---- fragment-linear weights
    int i = blk * 256 + tid;
    if (i < 147456) {                    // w0F
      int g = i / 36864, rem = i - g * 36864;
      int ks = rem >> 11, rem2 = rem & 2047;
      int cb = rem2 >> 9, e = rem2 & 511;
      int lane = e >> 3, j = e & 7;
      int n = g * 64 + cb * 16 + (lane & 15);
      int k = ks * 32 + (lane >> 4) * 8 + j;       // reordered k = kk*64+cc
      int kk = k >> 6, cc = k & 63;
      w0F[i] = (_Float16)w0[(cc * 9 + kk) * 256 + n];
      return;
    }
    i -= 147456;
    if (i < 196608) {                    // wF123
      int l = i >> 16, rem = i & 65535;
      int g = rem >> 14, rem2 = rem & 16383;
      int ks = rem2 >> 11, rem3 = rem2 & 2047;
      int cb = rem3 >> 9, e = rem3 & 511;
      int lane = e >> 3, j = e & 7;
      int n = g * 64 + cb * 16 + (lane & 15);
      int k = ks * 32 + (lane >> 4) * 8 + j;
      const float* w = (l == 0) ? w1 : (l == 1) ? w2 : w3;
      wF123[i] = (_Float16)w[k * 256 + n];
      return;
    }
    i -= 196608;
    if (i < 768) { int j = i / 256, c = i - j * 256; w4T[i] = w4[c * 3 + j]; return; }
    i -= 768;
    if (i < 1024) { int j = i >> 8, n = i & 255; w0tail[i] = w0[(576 + j) * 256 + n]; }
    return;
  }
  blk -= 1351;
  {                                      // ---- segmax (64 blocks)
    int p = blk * 256 + tid;
    if (p >= B_ * HW_) return;
    const float* a = attn + (size_t)p * S_;
    float best = a[0]; int bi = 0;
    for (int s = 1; s < S_; ++s) { float v = a[s]; if (v > best) { best = v; bi = s; } }
    segm[p] = bi;
  }
}

// ---------------------------------------------------------------------------
// topk: per (b,s) block, top-4 over 4096 pixels, reading coalesced attnT.
// ---------------------------------------------------------------------------
__global__ void topk_kernel(const float* __restrict__ attnT,
                            int* __restrict__ refc, float* __restrict__ wprob)
{
  int bid = blockIdx.x;                 // b*64 + s
  int tid = threadIdx.x;
  __shared__ float sv[256]; __shared__ int si[256];
  __shared__ float cvs[4]; __shared__ int cis[4];

  const float* col = attnT + (size_t)bid * 4096;
  float tv[4] = { -INFINITY, -INFINITY, -INFINITY, -INFINITY };
  int   ti[4] = { 0x7fffffff, 0x7fffffff, 0x7fffffff, 0x7fffffff };
  for (int j = tid; j < HW_; j += 256) {
    float v = col[j];
    if (v > tv[3]) {                    // equal value: existing (lower idx) wins
      tv[3] = v; ti[3] = j;
      #pragma unroll
      for (int x = 3; x > 0; --x) {
        if (tv[x] > tv[x-1] || (tv[x] == tv[x-1] && ti[x] < ti[x-1])) {
          float fv = tv[x]; tv[x] = tv[x-1]; tv[x-1] = fv;
          int   fi = ti[x]; ti[x] = ti[x-1]; ti[x-1] = fi;
        }
      }
    }
  }
  int ptr = 0;
  for (int r = 0; r < 4; ++r) {
    sv[tid] = (ptr < 4) ? tv[ptr] : -INFINITY;
    si[tid] = (ptr < 4) ? ti[ptr] : 0x7fffffff;
    __syncthreads();
    for (int o = 128; o; o >>= 1) {
      if (tid < o) {
        float v2 = sv[tid + o]; int i2 = si[tid + o];
        if (v2 > sv[tid] || (v2 == sv[tid] && i2 < si[tid])) { sv[tid] = v2; si[tid] = i2; }
      }
      __syncthreads();
    }
    if (tid == 0) { cvs[r] = sv[0]; cis[r] = si[0]; }
    __syncthreads();
    if (ptr < 4 && ti[ptr] == cis[r]) ptr++;
    __syncthreads();
  }
  if (tid == 0) {
    float ssum = cvs[0] + cvs[1] + cvs[2] + cvs[3];
    for (int k = 0; k < 4; ++k) { refc[bid*4 + k] = cis[k]; wprob[bid*4 + k] = cvs[k] / ssum; }
  }
}

// ---------------------------------------------------------------------------
// meta: per query build 8 MLP-row descriptors {src pixel-row, tail t[4], weight}
// ---------------------------------------------------------------------------
__global__ void meta_kernel(const float* __restrict__ coord, const float* __restrict__ cell,
                            const int* __restrict__ segm, const int* __restrict__ refc,
                            const float* __restrict__ wprob,
                            int* __restrict__ msrc, float4* __restrict__ mt,
                            float* __restrict__ mwgt)
{
  int q = blockIdx.x * 256 + threadIdx.x;
  if (q >= NQ_) return;
  int b = q >> 13;
  float c0 = coord[2*q], c1 = coord[2*q + 1];
  float rc0 = cell[2*q] * 64.0f, rc1 = cell[2*q + 1] * 64.0f;   // rel_cell

  // ---- attention branch ----
  float pf0 = (c0 + 1.0f) / 2.0f * 64.0f;
  float pf1 = (c1 + 1.0f) / 2.0f * 64.0f;
  int pc0 = (int)pf0, pc1 = (int)pf1;           // trunc (non-negative)
  pc0 = min(max(pc0, 0), 4095); pc1 = min(max(pc1, 0), 4095);
  int pc1d = pc0 * 64 + pc1;
  int sg = segm[b * 4096 + min(pc1d, 4095)];
  int base = (b * 64 + sg) * 4;
  #pragma unroll
  for (int k = 0; k < 4; ++k) {
    int rc = refc[base + k];
    int rrc = rc - pc1d;
    float rel0 = (float)(rrc >> 6) * 0.015625f;   // floor-div by 64 then /64
    float rel1 = (float)(rrc & 63) * 0.015625f;
    int r = q * 8 + k;
    msrc[r] = rc;                                  // batch-0 gather (faithful)
    mt[r] = make_float4(rel0, rel1, rc0, rc1);
    mwgt[r] = 0.5f * wprob[base + k];
  }

  // ---- local ensemble branch ----
  const float sg0[4] = { -1.f, -1.f, 1.f, 1.f };
  const float sg1[4] = { -1.f,  1.f, -1.f, 1.f };
  float area[4], rr0[4], rr1[4]; int srcs[4];
  #pragma unroll
  for (int t = 0; t < 4; ++t) {
    float o0 = sg0[t] * 0.015625f + 1e-6f;
    float o1 = sg1[t] * 0.015625f + 1e-6f;
    float cc0 = fminf(fmaxf(c0 + o0, -1.0f + 1e-6f), 1.0f - 1e-6f);
    float cc1 = fminf(fmaxf(c1 + o1, -1.0f + 1e-6f), 1.0f - 1e-6f);
    float vy = ((cc0 + 1.0f) * 64.0f - 1.0f) / 2.0f;
    float vx = ((cc1 + 1.0f) * 64.0f - 1.0f) / 2.0f;
    float fy = fminf(fmaxf(rintf(vy), 0.0f), 63.0f);   // rint (RNE) then clip
    float fx = fminf(fmaxf(rintf(vx), 0.0f), 63.0f);
    int iy = (int)fy, ix = (int)fx;
    srcs[t] = b * 4096 + iy * 64 + ix;
    float qc0 = -1.0f + (2.0f * (float)iy + 1.0f) / 64.0f;
    float qc1 = -1.0f + (2.0f * (float)ix + 1.0f) / 64.0f;
    float r0 = (c0 - qc0) * 64.0f;
    float r1 = (c1 - qc1) * 64.0f;
    rr0[t] = r0; rr1[t] = r1;
    area[t] = fabsf(r0 * r1) + 1e-9f;
  }
  float tot = area[0] + area[1] + area[2] + area[3];
  #pragma unroll
  for (int t = 0; t < 4; ++t) {
    int r = q * 8 + 4 + t;
    msrc[r] = srcs[t];
    mt[r] = make_float4(rr0[t], rr1[t], rc0, rc1);
    mwgt[r] = 0.5f * area[3 - t] / tot;            // wts = area[::-1]/tot
  }
}

// ---------------------------------------------------------------------------
// P0 GEMM (f16 MFMA): 1024 blocks = (b, y, quarter-row); 16 pixels x 256 cols.
// ---------------------------------------------------------------------------
__launch_bounds__(256, 4)
__global__ void p0_kernel(const _Float16* __restrict__ featT,
                          const _Float16* __restrict__ w0F,
                          float* __restrict__ P0)
{
  int blk = blockIdx.x;                 // b*256 + y*4 + qr
  int b = blk >> 8, y = (blk >> 2) & 63, qr = blk & 3;
  int tid = threadIdx.x;
  int wave = tid >> 6, lane = tid & 63, quad = lane >> 4, l16 = lane & 15;

  f32x4 acc[4];
  #pragma unroll
  for (int j = 0; j < 4; j++) { f32x4 z = {0.f,0.f,0.f,0.f}; acc[j] = z; }
  h8 zero8 = {0,0,0,0,0,0,0,0};

  #pragma unroll
  for (int ks = 0; ks < 18; ++ks) {     // K = 576 = 18*32
    int k0 = ks * 32 + quad * 8;
    int kk = k0 >> 6, cc = k0 & 63;
    int di = kk / 3 - 1, dj = kk - (kk / 3) * 3 - 1;
    int yy = y + di;
    int xx = qr * 16 + l16 + dj;
    h8 afr;
    if ((unsigned)yy < 64u && (unsigned)xx < 64u)
      afr = *(const h8*)(featT + ((((size_t)b * 64 + yy) * 64 + xx) << 6) + cc);
    else
      afr = zero8;
    #pragma unroll
    for (int cb = 0; cb < 4; cb++) {
      h8 bfr = *(const h8*)(w0F + ((((size_t)wave * 18 + ks) * 4 + cb) << 9) + lane * 8);
      acc[cb] = __builtin_amdgcn_mfma_f32_16x16x32_f16(afr, bfr, acc[cb], 0, 0, 0);
    }
  }
  int pixbase = (b * 4096 + y * 64 + qr * 16);
  #pragma unroll
  for (int cb = 0; cb < 4; cb++)
    #pragma unroll
    for (int i = 0; i < 4; i++) {
      int m = quad * 4 + i;
      int n = wave * 64 + cb * 16 + l16;
      P0[((size_t)(pixbase + m) << 8) + n] = acc[cb][i];
    }
}

// ---------------------------------------------------------------------------
// Fused MLP trunk (f16 MFMA): explicit software pipeline — depth-2 register
// prefetch for global B-frags, depth-1 for LDS A-frags; seed gather batched
// 8-deep. 64 rows/block, 4 waves x 64 cols, single in-place LDS buffer.
// launch_bounds(256,3): ~170 VGPR budget for the prefetch buffers.
// ---------------------------------------------------------------------------
__launch_bounds__(256, 3)
__global__ void trunk_kernel(const float* __restrict__ P0,
                             const int* __restrict__ msrc,
                             const float4* __restrict__ mt,
                             const float* __restrict__ mwgt,
                             const float* __restrict__ w0tail,
                             const float* __restrict__ b0,
                             const _Float16* __restrict__ wF123,
                             const float* __restrict__ b1,
                             const float* __restrict__ b2,
                             const float* __restrict__ b3,
                             const float* __restrict__ w4T,
                             const float* __restrict__ b4,
                             float* __restrict__ out)
{
  __shared__ _Float16 hS[64][264];      // +8 pad; 16B-aligned rows (528 B)
  __shared__ float part_s[64][4][4];
  __shared__ float red[64][4];

  int tid = threadIdx.x;
  int rowbase = blockIdx.x * 64;
  int wv = tid >> 6;

  // ---- seed: h0 = relu(P0[src] + t . w0tail + b0); 8-deep batched gather ----
  {
    int cg = tid & 63;
    float4 wt0 = ((const float4*)w0tail)[cg];
    float4 wt1 = ((const float4*)w0tail)[64 + cg];
    float4 wt2 = ((const float4*)w0tail)[128 + cg];
    float4 wt3 = ((const float4*)w0tail)[192 + cg];
    float4 bb  = ((const float4*)b0)[cg];
    #pragma unroll
    for (int half = 0; half < 2; ++half) {
      int srcs[8]; float4 ts[8];
      #pragma unroll
      for (int i = 0; i < 8; ++i) {
        int r = rowbase + half * 32 + wv + i * 4;
        srcs[i] = msrc[r];
        ts[i] = mt[r];
      }
      #pragma unroll
      for (int i = 0; i < 8; ++i) {
        int rr = half * 32 + wv + i * 4;
        float4 t = ts[i];
        float4 p = ((const float4*)(P0 + ((size_t)srcs[i] << 8)))[cg];
        h4 v;
        v[0] = (_Float16)fmaxf(p.x + t.x*wt0.x + t.y*wt1.x + t.z*wt2.x + t.w*wt3.x + bb.x, 0.0f);
        v[1] = (_Float16)fmaxf(p.y + t.x*wt0.y + t.y*wt1.y + t.z*wt2.y + t.w*wt3.y + bb.y, 0.0f);
        v[2] = (_Float16)fmaxf(p.z + t.x*wt0.z + t.y*wt1.z + t.z*wt2.z + t.w*wt3.z + bb.z, 0.0f);
        v[3] = (_Float16)fmaxf(p.w + t.x*wt0.w + t.y*wt1.w + t.z*wt2.w + t.w*wt3.w + bb.w, 0.0f);
        *(h4*)(&hS[rr][cg * 4]) = v;
      }
    }
  }
  __syncthreads();

  int wave = tid >> 6, lane = tid & 63, quad = lane >> 4, l16 = lane & 15;

  #pragma unroll 1
  for (int l = 0; l < 3; ++l) {
    const _Float16* wL = wF123 + (((size_t)l * 4 + wave) << 14);
    const float* bia = (l == 0) ? b1 : (l == 1) ? b2 : b3;
    f32x4 acc[4][4];
    #pragma unroll
    for (int i = 0; i < 4; i++)
      #pragma unroll
      for (int j = 0; j < 4; j++) { f32x4 z = {0.f,0.f,0.f,0.f}; acc[i][j] = z; }

    h8 aP[2][4], bP[2][4];
    #pragma unroll
    for (int cb = 0; cb < 4; cb++) {    // B prefetch depth 2
      bP[0][cb] = *(const h8*)(wL + (((size_t)0 * 4 + cb) << 9) + lane * 8);
      bP[1][cb] = *(const h8*)(wL + (((size_t)1 * 4 + cb) << 9) + lane * 8);
    }
    #pragma unroll
    for (int rb = 0; rb < 4; rb++)      // A prefetch depth 1
      aP[0][rb] = *(const h8*)(&hS[rb * 16 + l16][quad * 8]);

    #pragma unroll
    for (int ks = 0; ks < 8; ++ks) {
      int cur = ks & 1, nxt = cur ^ 1;
      if (ks + 1 < 8) {                 // A for ks+1 (LDS)
        int k0 = (ks + 1) * 32 + quad * 8;
        #pragma unroll
        for (int rb = 0; rb < 4; rb++)
          aP[nxt][rb] = *(const h8*)(&hS[rb * 16 + l16][k0]);
      }
      #pragma unroll
      for (int rb = 0; rb < 4; rb++)
        #pragma unroll
        for (int cb = 0; cb < 4; cb++)
          acc[rb][cb] = __builtin_amdgcn_mfma_f32_16x16x32_f16(aP[cur][rb], bP[cur][cb], acc[rb][cb], 0, 0, 0);
      if (ks + 2 < 8) {                 // B for ks+2 (global) into cur slot
        #pragma unroll
        for (int cb = 0; cb < 4; cb++)
          bP[cur][cb] = *(const h8*)(wL + (((size_t)(ks + 2) * 4 + cb) << 9) + lane * 8);
      }
    }
    __syncthreads();                    // all reads of hS complete
    #pragma unroll
    for (int rb = 0; rb < 4; rb++)
      #pragma unroll
      for (int cb = 0; cb < 4; cb++) {
        int n = wave * 64 + cb * 16 + l16;
        float bv = bia[n];
        #pragma unroll
        for (int i = 0; i < 4; i++) {
          int m = rb * 16 + quad * 4 + i;
          hS[m][n] = (_Float16)fmaxf(acc[rb][cb][i] + bv, 0.0f);   // in-place
        }
      }
    __syncthreads();                    // writes visible before next reads
  }

  // ---- epilogue: y = h3 @ w4 + b4, weight, reduce 8 rows/query ----
  {
    int row = tid >> 2, part = tid & 3;
    const _Float16* hr = &hS[row][part * 64];
    float s0 = 0.f, s1 = 0.f, s2 = 0.f;
    #pragma unroll
    for (int c8 = 0; c8 < 64; c8 += 8) {
      h8 hv = *(const h8*)(hr + c8);
      #pragma unroll
      for (int u = 0; u < 8; ++u) {
        float h = (float)hv[u];
        int c = part * 64 + c8 + u;
        s0 += h * w4T[c];
        s1 += h * w4T[256 + c];
        s2 += h * w4T[512 + c];
      }
    }
    part_s[row][part][0] = s0; part_s[row][part][1] = s1; part_s[row][part][2] = s2;
  }
  __syncthreads();
  if (tid < 64) {
    float wgt = mwgt[rowbase + tid];
    red[tid][0] = (part_s[tid][0][0] + part_s[tid][1][0] + part_s[tid][2][0] + part_s[tid][3][0] + b4[0]) * wgt;
    red[tid][1] = (part_s[tid][0][1] + part_s[tid][1][1] + part_s[tid][2][1] + part_s[tid][3][1] + b4[1]) * wgt;
    red[tid][2] = (part_s[tid][0][2] + part_s[tid][1][2] + part_s[tid][2][2] + part_s[tid][3][2] + b4[2]) * wgt;
  }
  __syncthreads();
  if (tid < 8) {
    int q = (rowbase >> 3) + tid;       // global query index b*N+n
    float o0 = 0.f, o1 = 0.f, o2 = 0.f;
    #pragma unroll
    for (int j = 0; j < 8; j++) {
      o0 += red[tid * 8 + j][0];
      o1 += red[tid * 8 + j][1];
      o2 += red[tid * 8 + j][2];
    }
    out[q * 3 + 0] = o0;
    out[q * 3 + 1] = o1;
    out[q * 3 + 2] = o2;
  }
}

// ---------------------------------------------------------------------------
extern "C" void kernel_launch(void* const* d_in, const int* in_sizes, int n_in,
                              void* d_out, int out_size, void* d_ws, size_t ws_size,
                              hipStream_t stream)
{
  const float* feat  = (const float*)d_in[0];
  const float* attn  = (const float*)d_in[1];
  const float* coord = (const float*)d_in[2];
  const float* cell  = (const float*)d_in[3];
  const float* w0 = (const float*)d_in[4];
  const float* b0 = (const float*)d_in[5];
  const float* w1 = (const float*)d_in[6];
  const float* b1 = (const float*)d_in[7];
  const float* w2 = (const float*)d_in[8];
  const float* b2 = (const float*)d_in[9];
  const float* w3 = (const float*)d_in[10];
  const float* b3 = (const float*)d_in[11];
  const float* w4 = (const float*)d_in[12];
  const float* b4 = (const float*)d_in[13];
  float* out = (float*)d_out;           // reference output dtype = float32

  char* ws = (char*)d_ws;
  size_t off = 0;
  auto alloc = [&](size_t bytes) -> char* {
    char* p = ws + off;
    off += (bytes + 255) & ~(size_t)255;
    return p;
  };
  _Float16* featT = (_Float16*)alloc((size_t)B_ * H_ * W_ * D_ * 2);  //  2.10 MB
  _Float16* w0F   = (_Float16*)alloc((size_t)147456 * 2);             //  0.29 MB
  _Float16* wF123 = (_Float16*)alloc((size_t)196608 * 2);             //  0.39 MB
  float*  w4T   = (float*)alloc((size_t)3 * 256 * 4);
  float*  w0tl  = (float*)alloc((size_t)4 * 256 * 4);
  float*  attnT = (float*)alloc((size_t)B_ * S_ * HW_ * 4);           //  4.2 MB
  int*    segm  = (int*)alloc((size_t)B_ * HW_ * 4);                  //  64 KB
  int*    refc  = (int*)alloc((size_t)B_ * S_ * K_ * 4);
  float*  wprob = (float*)alloc((size_t)B_ * S_ * K_ * 4);
  float*  P0    = (float*)alloc((size_t)B_ * HW_ * 256 * 4);          // 16.8 MB
  int*    msrc  = (int*)alloc((size_t)ROWS_ * 4);                     //  1.0 MB
  float4* mtb   = (float4*)alloc((size_t)ROWS_ * 16);                 //  4.2 MB
  float*  mwgt  = (float*)alloc((size_t)ROWS_ * 4);                   //  1.0 MB
  (void)in_sizes; (void)n_in; (void)out_size; (void)ws_size;          // ~31 MB total

  fused_prep_kernel<<<1927, 256, 0, stream>>>(feat, attn, w0, w1, w2, w3, w4,
                                              featT, attnT, w0F, wF123, w4T, w0tl, segm);
  topk_kernel<<<256, 256, 0, stream>>>(attnT, refc, wprob);
  meta_kernel<<<128, 256, 0, stream>>>(coord, cell, segm, refc, wprob, msrc, mtb, mwgt);
  p0_kernel<<<1024, 256, 0, stream>>>(featT, w0F, P0);
  trunk_kernel<<<4096, 256, 0, stream>>>(P0, msrc, mtb, mwgt, w0tl, b0, wF123,
                                         b1, b2, b3, w4T, b4, out);
}

// Round 9
// 302.222 us; speedup vs baseline: 1.6056x; 1.0928x over previous
//
#include <hip/hip_runtime.h>
#include <hip/hip_bf16.h>
#include <math.h>
#include <stdint.h>

#define B_ 4
#define D_ 64
#define H_ 64
#define W_ 64
#define S_ 64
#define N_ 8192
#define K_ 4
#define HID_ 256
#define HW_ 4096
#define NQ_ (B_*N_)        // 32768 queries
#define ROWS_ (NQ_*8)      // 262144 MLP rows (4 attn + 4 local per query)

typedef _Float16 h8   __attribute__((ext_vector_type(8)));
typedef _Float16 h4   __attribute__((ext_vector_type(4)));
typedef float    f32x4 __attribute__((ext_vector_type(4)));

// ---------------------------------------------------------------------------
// fused prep: [0,256) feat transpose | [256,512) attn transpose |
// [512,1863) weight repack | [1863,1927) segmax.  One launch, no deps.
// ---------------------------------------------------------------------------
__global__ void fused_prep_kernel(const float* __restrict__ feat,
                                  const float* __restrict__ attn,
                                  const float* __restrict__ w0,
                                  const float* __restrict__ w1,
                                  const float* __restrict__ w2,
                                  const float* __restrict__ w3,
                                  const float* __restrict__ w4,
                                  _Float16* __restrict__ featT,
                                  float* __restrict__ attnT,
                                  _Float16* __restrict__ w0F,
                                  _Float16* __restrict__ wF123,
                                  float* __restrict__ w4T,
                                  float* __restrict__ w0tail,
                                  int* __restrict__ segm)
{
  __shared__ float t[64][65];
  int blk = blockIdx.x;
  int tid = threadIdx.x;

  if (blk < 256) {                       // ---- feat (B,D,H,W) -> featT[b][y][x][c]
    int b = blk >> 6, y = blk & 63;
    for (int p = 0; p < 16; ++p) {
      int c = p * 4 + (tid >> 6), x = tid & 63;
      t[c][x] = feat[(((size_t)b * 64 + c) << 12) + (y << 6) + x];
    }
    __syncthreads();
    for (int p = 0; p < 16; ++p) {
      int x = p * 4 + (tid >> 6), c = tid & 63;
      featT[((((size_t)b * 64 + y) * 64 + x) << 6) + c] = (_Float16)t[c][x];
    }
    return;
  }
  blk -= 256;
  if (blk < 256) {                       // ---- attn (B,HW,S) -> attnT (B,S,HW)
    int b = blk >> 6, j0 = (blk & 63) << 6;
    for (int idx = tid; idx < 4096; idx += 256) {
      int r = idx >> 6, c = idx & 63;
      t[r][c] = attn[((size_t)(b * 4096 + j0 + r)) * 64 + c];
    }
    __syncthreads();
    for (int idx = tid; idx < 4096; idx += 256) {
      int s = idx >> 6, r = idx & 63;
      attnT[((size_t)(b * 64 + s)) * 4096 + j0 + r] = t[r][s];
    }
    return;
  }
  blk -= 256;
  if (blk < 1351) {                      // ---- fragment-linear weights
    int i = blk * 256 + tid;
    if (i < 147456) {                    // w0F
      int g = i / 36864, rem = i - g * 36864;
      int ks = rem >> 11, rem2 = rem & 2047;
      int cb = rem2 >> 9, e = rem2 & 511;
      int lane = e >> 3, j = e & 7;
      int n = g * 64 + cb * 16 + (lane & 15);
      int k = ks * 32 + (lane >> 4) * 8 + j;       // reordered k = kk*64+cc
      int kk = k >> 6, cc = k & 63;
      w0F[i] = (_Float16)w0[(cc * 9 + kk) * 256 + n];
      return;
    }
    i -= 147456;
    if (i < 196608) {                    // wF123
      int l = i >> 16, rem = i & 65535;
      int g = rem >> 14, rem2 = rem & 16383;
      int ks = rem2 >> 11, rem3 = rem2 & 2047;
      int cb = rem3 >> 9, e = rem3 & 511;
      int lane = e >> 3, j = e & 7;
      int n = g * 64 + cb * 16 + (lane & 15);
      int k = ks * 32 + (lane >> 4) * 8 + j;
      const float* w = (l == 0) ? w1 : (l == 1) ? w2 : w3;
      wF123[i] = (_Float16)w[k * 256 + n];
      return;
    }
    i -= 196608;
    if (i < 768) { int j = i / 256, c = i - j * 256; w4T[i] = w4[c * 3 + j]; return; }
    i -= 768;
    if (i < 1024) { int j = i >> 8, n = i & 255; w0tail[i] = w0[(576 + j) * 256 + n]; }
    return;
  }
  blk -= 1351;
  {                                      // ---- segmax (64 blocks)
    int p = blk * 256 + tid;
    if (p >= B_ * HW_) return;
    const float* a = attn + (size_t)p * S_;
    float best = a[0]; int bi = 0;
    for (int s = 1; s < S_; ++s) { float v = a[s]; if (v > best) { best = v; bi = s; } }
    segm[p] = bi;
  }
}

// ---------------------------------------------------------------------------
// topk: per (b,s) block, top-4 over 4096 pixels, reading coalesced attnT.
// ---------------------------------------------------------------------------
__global__ void topk_kernel(const float* __restrict__ attnT,
                            int* __restrict__ refc, float* __restrict__ wprob)
{
  int bid = blockIdx.x;                 // b*64 + s
  int tid = threadIdx.x;
  __shared__ float sv[256]; __shared__ int si[256];
  __shared__ float cvs[4]; __shared__ int cis[4];

  const float* col = attnT + (size_t)bid * 4096;
  float tv[4] = { -INFINITY, -INFINITY, -INFINITY, -INFINITY };
  int   ti[4] = { 0x7fffffff, 0x7fffffff, 0x7fffffff, 0x7fffffff };
  for (int j = tid; j < HW_; j += 256) {
    float v = col[j];
    if (v > tv[3]) {                    // equal value: existing (lower idx) wins
      tv[3] = v; ti[3] = j;
      #pragma unroll
      for (int x = 3; x > 0; --x) {
        if (tv[x] > tv[x-1] || (tv[x] == tv[x-1] && ti[x] < ti[x-1])) {
          float fv = tv[x]; tv[x] = tv[x-1]; tv[x-1] = fv;
          int   fi = ti[x]; ti[x] = ti[x-1]; ti[x-1] = fi;
        }
      }
    }
  }
  int ptr = 0;
  for (int r = 0; r < 4; ++r) {
    sv[tid] = (ptr < 4) ? tv[ptr] : -INFINITY;
    si[tid] = (ptr < 4) ? ti[ptr] : 0x7fffffff;
    __syncthreads();
    for (int o = 128; o; o >>= 1) {
      if (tid < o) {
        float v2 = sv[tid + o]; int i2 = si[tid + o];
        if (v2 > sv[tid] || (v2 == sv[tid] && i2 < si[tid])) { sv[tid] = v2; si[tid] = i2; }
      }
      __syncthreads();
    }
    if (tid == 0) { cvs[r] = sv[0]; cis[r] = si[0]; }
    __syncthreads();
    if (ptr < 4 && ti[ptr] == cis[r]) ptr++;
    __syncthreads();
  }
  if (tid == 0) {
    float ssum = cvs[0] + cvs[1] + cvs[2] + cvs[3];
    for (int k = 0; k < 4; ++k) { refc[bid*4 + k] = cis[k]; wprob[bid*4 + k] = cvs[k] / ssum; }
  }
}

// ---------------------------------------------------------------------------
// meta: per query build 8 MLP-row descriptors {src pixel-row, tail t[4], weight}
// ---------------------------------------------------------------------------
__global__ void meta_kernel(const float* __restrict__ coord, const float* __restrict__ cell,
                            const int* __restrict__ segm, const int* __restrict__ refc,
                            const float* __restrict__ wprob,
                            int* __restrict__ msrc, float4* __restrict__ mt,
                            float* __restrict__ mwgt)
{
  int q = blockIdx.x * 256 + threadIdx.x;
  if (q >= NQ_) return;
  int b = q >> 13;
  float c0 = coord[2*q], c1 = coord[2*q + 1];
  float rc0 = cell[2*q] * 64.0f, rc1 = cell[2*q + 1] * 64.0f;   // rel_cell

  // ---- attention branch ----
  float pf0 = (c0 + 1.0f) / 2.0f * 64.0f;
  float pf1 = (c1 + 1.0f) / 2.0f * 64.0f;
  int pc0 = (int)pf0, pc1 = (int)pf1;           // trunc (non-negative)
  pc0 = min(max(pc0, 0), 4095); pc1 = min(max(pc1, 0), 4095);
  int pc1d = pc0 * 64 + pc1;
  int sg = segm[b * 4096 + min(pc1d, 4095)];
  int base = (b * 64 + sg) * 4;
  #pragma unroll
  for (int k = 0; k < 4; ++k) {
    int rc = refc[base + k];
    int rrc = rc - pc1d;
    float rel0 = (float)(rrc >> 6) * 0.015625f;   // floor-div by 64 then /64
    float rel1 = (float)(rrc & 63) * 0.015625f;
    int r = q * 8 + k;
    msrc[r] = rc;                                  // batch-0 gather (faithful)
    mt[r] = make_float4(rel0, rel1, rc0, rc1);
    mwgt[r] = 0.5f * wprob[base + k];
  }

  // ---- local ensemble branch ----
  const float sg0[4] = { -1.f, -1.f, 1.f, 1.f };
  const float sg1[4] = { -1.f,  1.f, -1.f, 1.f };
  float area[4], rr0[4], rr1[4]; int srcs[4];
  #pragma unroll
  for (int t = 0; t < 4; ++t) {
    float o0 = sg0[t] * 0.015625f + 1e-6f;
    float o1 = sg1[t] * 0.015625f + 1e-6f;
    float cc0 = fminf(fmaxf(c0 + o0, -1.0f + 1e-6f), 1.0f - 1e-6f);
    float cc1 = fminf(fmaxf(c1 + o1, -1.0f + 1e-6f), 1.0f - 1e-6f);
    float vy = ((cc0 + 1.0f) * 64.0f - 1.0f) / 2.0f;
    float vx = ((cc1 + 1.0f) * 64.0f - 1.0f) / 2.0f;
    float fy = fminf(fmaxf(rintf(vy), 0.0f), 63.0f);   // rint (RNE) then clip
    float fx = fminf(fmaxf(rintf(vx), 0.0f), 63.0f);
    int iy = (int)fy, ix = (int)fx;
    srcs[t] = b * 4096 + iy * 64 + ix;
    float qc0 = -1.0f + (2.0f * (float)iy + 1.0f) / 64.0f;
    float qc1 = -1.0f + (2.0f * (float)ix + 1.0f) / 64.0f;
    float r0 = (c0 - qc0) * 64.0f;
    float r1 = (c1 - qc1) * 64.0f;
    rr0[t] = r0; rr1[t] = r1;
    area[t] = fabsf(r0 * r1) + 1e-9f;
  }
  float tot = area[0] + area[1] + area[2] + area[3];
  #pragma unroll
  for (int t = 0; t < 4; ++t) {
    int r = q * 8 + 4 + t;
    msrc[r] = srcs[t];
    mt[r] = make_float4(rr0[t], rr1[t], rc0, rc1);
    mwgt[r] = 0.5f * area[3 - t] / tot;            // wts = area[::-1]/tot
  }
}

// ---------------------------------------------------------------------------
// P0 GEMM (f16 MFMA): 1024 blocks = (b, y, quarter-row); 16 pixels x 256 cols.
// ---------------------------------------------------------------------------
__launch_bounds__(256, 4)
__global__ void p0_kernel(const _Float16* __restrict__ featT,
                          const _Float16* __restrict__ w0F,
                          float* __restrict__ P0)
{
  int blk = blockIdx.x;                 // b*256 + y*4 + qr
  int b = blk >> 8, y = (blk >> 2) & 63, qr = blk & 3;
  int tid = threadIdx.x;
  int wave = tid >> 6, lane = tid & 63, quad = lane >> 4, l16 = lane & 15;

  f32x4 acc[4];
  #pragma unroll
  for (int j = 0; j < 4; j++) { f32x4 z = {0.f,0.f,0.f,0.f}; acc[j] = z; }
  h8 zero8 = {0,0,0,0,0,0,0,0};

  #pragma unroll
  for (int ks = 0; ks < 18; ++ks) {     // K = 576 = 18*32
    int k0 = ks * 32 + quad * 8;
    int kk = k0 >> 6, cc = k0 & 63;
    int di = kk / 3 - 1, dj = kk - (kk / 3) * 3 - 1;
    int yy = y + di;
    int xx = qr * 16 + l16 + dj;
    h8 afr;
    if ((unsigned)yy < 64u && (unsigned)xx < 64u)
      afr = *(const h8*)(featT + ((((size_t)b * 64 + yy) * 64 + xx) << 6) + cc);
    else
      afr = zero8;
    #pragma unroll
    for (int cb = 0; cb < 4; cb++) {
      h8 bfr = *(const h8*)(w0F + ((((size_t)wave * 18 + ks) * 4 + cb) << 9) + lane * 8);
      acc[cb] = __builtin_amdgcn_mfma_f32_16x16x32_f16(afr, bfr, acc[cb], 0, 0, 0);
    }
  }
  int pixbase = (b * 4096 + y * 64 + qr * 16);
  #pragma unroll
  for (int cb = 0; cb < 4; cb++)
    #pragma unroll
    for (int i = 0; i < 4; i++) {
      int m = quad * 4 + i;
      int n = wave * 64 + cb * 16 + l16;
      P0[((size_t)(pixbase + m) << 8) + n] = acc[cb][i];
    }
}

// ---------------------------------------------------------------------------
// Fused MLP trunk, M=128 tile (f16 MFMA): each of 4 waves owns 64 cols x 128
// rows (acc 8x4 f32x4 = 128 VGPR). Per K-step: 4 B-loads feed 32 MFMAs
// (~147 cyc) -- covers L2 latency; weight L2 traffic halves vs M=64.
// Single in-place LDS activation buffer; 2 blocks/CU at 72.7 KB.
// ---------------------------------------------------------------------------
__launch_bounds__(256, 2)
__global__ void trunk_kernel(const float* __restrict__ P0,
                             const int* __restrict__ msrc,
                             const float4* __restrict__ mt,
                             const float* __restrict__ mwgt,
                             const float* __restrict__ w0tail,
                             const float* __restrict__ b0,
                             const _Float16* __restrict__ wF123,
                             const float* __restrict__ b1,
                             const float* __restrict__ b2,
                             const float* __restrict__ b3,
                             const float* __restrict__ w4T,
                             const float* __restrict__ b4,
                             float* __restrict__ out)
{
  __shared__ _Float16 hS[128][264];     // +8 pad; 67.6 KB
  __shared__ float part_s[128][2][3];   // 3 KB
  __shared__ float red[128][4];         // 2 KB

  int tid = threadIdx.x;
  int rowbase = blockIdx.x * 128;
  int wv = tid >> 6;

  // ---- seed: h0 = relu(P0[src] + t . w0tail + b0); 8-deep batched gather ----
  {
    int cg = tid & 63;
    float4 wt0 = ((const float4*)w0tail)[cg];
    float4 wt1 = ((const float4*)w0tail)[64 + cg];
    float4 wt2 = ((const float4*)w0tail)[128 + cg];
    float4 wt3 = ((const float4*)w0tail)[192 + cg];
    float4 bb  = ((const float4*)b0)[cg];
    #pragma unroll 1
    for (int g = 0; g < 4; ++g) {
      int srcs[8]; float4 ts[8];
      #pragma unroll
      for (int i = 0; i < 8; ++i) {
        int r = rowbase + g * 32 + i * 4 + wv;
        srcs[i] = msrc[r];
        ts[i] = mt[r];
      }
      #pragma unroll
      for (int i = 0; i < 8; ++i) {
        int rr = g * 32 + i * 4 + wv;
        float4 t = ts[i];
        float4 p = ((const float4*)(P0 + ((size_t)srcs[i] << 8)))[cg];
        h4 v;
        v[0] = (_Float16)fmaxf(p.x + t.x*wt0.x + t.y*wt1.x + t.z*wt2.x + t.w*wt3.x + bb.x, 0.0f);
        v[1] = (_Float16)fmaxf(p.y + t.x*wt0.y + t.y*wt1.y + t.z*wt2.y + t.w*wt3.y + bb.y, 0.0f);
        v[2] = (_Float16)fmaxf(p.z + t.x*wt0.z + t.y*wt1.z + t.z*wt2.z + t.w*wt3.z + bb.z, 0.0f);
        v[3] = (_Float16)fmaxf(p.w + t.x*wt0.w + t.y*wt1.w + t.z*wt2.w + t.w*wt3.w + bb.w, 0.0f);
        *(h4*)(&hS[rr][cg * 4]) = v;
      }
    }
  }
  __syncthreads();

  int wave = tid >> 6, lane = tid & 63, quad = lane >> 4, l16 = lane & 15;

  #pragma unroll 1
  for (int l = 0; l < 3; ++l) {
    const _Float16* wL = wF123 + (((size_t)l * 4 + wave) << 14);
    const float* bia = (l == 0) ? b1 : (l == 1) ? b2 : b3;
    f32x4 acc[8][4];
    #pragma unroll
    for (int i = 0; i < 8; i++)
      #pragma unroll
      for (int j = 0; j < 4; j++) { f32x4 z = {0.f,0.f,0.f,0.f}; acc[i][j] = z; }

    h8 bP[2][4];
    #pragma unroll
    for (int cb = 0; cb < 4; cb++) {    // B prefetch depth 2
      bP[0][cb] = *(const h8*)(wL + (((size_t)0 * 4 + cb) << 9) + lane * 8);
      bP[1][cb] = *(const h8*)(wL + (((size_t)1 * 4 + cb) << 9) + lane * 8);
    }

    #pragma unroll
    for (int ks = 0; ks < 8; ++ks) {
      int cur = ks & 1;
      int k0 = ks * 32 + quad * 8;
      h8 afr[8];
      #pragma unroll
      for (int rb = 0; rb < 8; rb++)
        afr[rb] = *(const h8*)(&hS[rb * 16 + l16][k0]);
      #pragma unroll
      for (int rb = 0; rb < 8; rb++)
        #pragma unroll
        for (int cb = 0; cb < 4; cb++)
          acc[rb][cb] = __builtin_amdgcn_mfma_f32_16x16x32_f16(afr[rb], bP[cur][cb], acc[rb][cb], 0, 0, 0);
      if (ks + 2 < 8) {                 // B for ks+2 into the slot just freed
        #pragma unroll
        for (int cb = 0; cb < 4; cb++)
          bP[cur][cb] = *(const h8*)(wL + (((size_t)(ks + 2) * 4 + cb) << 9) + lane * 8);
      }
    }
    __syncthreads();                    // all reads of hS complete
    #pragma unroll
    for (int rb = 0; rb < 8; rb++)
      #pragma unroll
      for (int cb = 0; cb < 4; cb++) {
        int n = wave * 64 + cb * 16 + l16;
        float bv = bia[n];
        #pragma unroll
        for (int i = 0; i < 4; i++) {
          int m = rb * 16 + quad * 4 + i;
          hS[m][n] = (_Float16)fmaxf(acc[rb][cb][i] + bv, 0.0f);   // in-place
        }
      }
    __syncthreads();                    // writes visible before next reads
  }

  // ---- epilogue: y = h3 @ w4 + b4, weight, reduce 8 rows/query ----
  {
    int row = tid >> 1, part = tid & 1;
    const _Float16* hr = &hS[row][part * 128];
    float s0 = 0.f, s1 = 0.f, s2 = 0.f;
    #pragma unroll
    for (int c8 = 0; c8 < 128; c8 += 8) {
      h8 hv = *(const h8*)(hr + c8);
      #pragma unroll
      for (int u = 0; u < 8; ++u) {
        float h = (float)hv[u];
        int c = part * 128 + c8 + u;
        s0 += h * w4T[c];
        s1 += h * w4T[256 + c];
        s2 += h * w4T[512 + c];
      }
    }
    part_s[row][part][0] = s0; part_s[row][part][1] = s1; part_s[row][part][2] = s2;
  }
  __syncthreads();
  if (tid < 128) {
    float wgt = mwgt[rowbase + tid];
    red[tid][0] = (part_s[tid][0][0] + part_s[tid][1][0] + b4[0]) * wgt;
    red[tid][1] = (part_s[tid][0][1] + part_s[tid][1][1] + b4[1]) * wgt;
    red[tid][2] = (part_s[tid][0][2] + part_s[tid][1][2] + b4[2]) * wgt;
  }
  __syncthreads();
  if (tid < 16) {
    int q = blockIdx.x * 16 + tid;      // global query index b*N+n
    float o0 = 0.f, o1 = 0.f, o2 = 0.f;
    #pragma unroll
    for (int j = 0; j < 8; j++) {
      o0 += red[tid * 8 + j][0];
      o1 += red[tid * 8 + j][1];
      o2 += red[tid * 8 + j][2];
    }
    out[q * 3 + 0] = o0;
    out[q * 3 + 1] = o1;
    out[q * 3 + 2] = o2;
  }
}

// ---------------------------------------------------------------------------
extern "C" void kernel_launch(void* const* d_in, const int* in_sizes, int n_in,
                              void* d_out, int out_size, void* d_ws, size_t ws_size,
                              hipStream_t stream)
{
  const float* feat  = (const float*)d_in[0];
  const float* attn  = (const float*)d_in[1];
  const float* coord = (const float*)d_in[2];
  const float* cell  = (const float*)d_in[3];
  const float* w0 = (const float*)d_in[4];
  const float* b0 = (const float*)d_in[5];
  const float* w1 = (const float*)d_in[6];
  const float* b1 = (const float*)d_in[7];
  const float* w2 = (const float*)d_in[8];
  const float* b2 = (const float*)d_in[9];
  const float* w3 = (const float*)d_in[10];
  const float* b3 = (const float*)d_in[11];
  const float* w4 = (const float*)d_in[12];
  const float* b4 = (const float*)d_in[13];
  float* out = (float*)d_out;           // reference output dtype = float32

  char* ws = (char*)d_ws;
  size_t off = 0;
  auto alloc = [&](size_t bytes) -> char* {
    char* p = ws + off;
    off += (bytes + 255) & ~(size_t)255;
    return p;
  };
  _Float16* featT = (_Float16*)alloc((size_t)B_ * H_ * W_ * D_ * 2);  //  2.10 MB
  _Float16* w0F   = (_Float16*)alloc((size_t)147456 * 2);             //  0.29 MB
  _Float16* wF123 = (_Float16*)alloc((size_t)196608 * 2);             //  0.39 MB
  float*  w4T   = (float*)alloc((size_t)3 * 256 * 4);
  float*  w0tl  = (float*)alloc((size_t)4 * 256 * 4);
  float*  attnT = (float*)alloc((size_t)B_ * S_ * HW_ * 4);           //  4.2 MB
  int*    segm  = (int*)alloc((size_t)B_ * HW_ * 4);                  //  64 KB
  int*    refc  = (int*)alloc((size_t)B_ * S_ * K_ * 4);
  float*  wprob = (float*)alloc((size_t)B_ * S_ * K_ * 4);
  float*  P0    = (float*)alloc((size_t)B_ * HW_ * 256 * 4);          // 16.8 MB
  int*    msrc  = (int*)alloc((size_t)ROWS_ * 4);                     //  1.0 MB
  float4* mtb   = (float4*)alloc((size_t)ROWS_ * 16);                 //  4.2 MB
  float*  mwgt  = (float*)alloc((size_t)ROWS_ * 4);                   //  1.0 MB
  (void)in_sizes; (void)n_in; (void)out_size; (void)ws_size;          // ~31 MB total

  fused_prep_kernel<<<1927, 256, 0, stream>>>(feat, attn, w0, w1, w2, w3, w4,
                                              featT, attnT, w0F, wF123, w4T, w0tl, segm);
  topk_kernel<<<256, 256, 0, stream>>>(attnT, refc, wprob);
  meta_kernel<<<128, 256, 0, stream>>>(coord, cell, segm, refc, wprob, msrc, mtb, mwgt);
  p0_kernel<<<1024, 256, 0, stream>>>(featT, w0F, P0);
  trunk_kernel<<<2048, 256, 0, stream>>>(P0, msrc, mtb, mwgt, w0tl, b0, wF123,
                                         b1, b2, b3, w4T, b4, out);
}

// Round 10
// 270.463 us; speedup vs baseline: 1.7942x; 1.1174x over previous
//
#include <hip/hip_runtime.h>
#include <hip/hip_bf16.h>
#include <math.h>
#include <stdint.h>

#define B_ 4
#define D_ 64
#define H_ 64
#define W_ 64
#define S_ 64
#define N_ 8192
#define K_ 4
#define HID_ 256
#define HW_ 4096
#define NQ_ (B_*N_)        // 32768 queries
#define ROWS_ (NQ_*8)      // 262144 MLP rows (4 attn + 4 local per query)

typedef _Float16 h8   __attribute__((ext_vector_type(8)));
typedef _Float16 h4   __attribute__((ext_vector_type(4)));
typedef float    f32x4 __attribute__((ext_vector_type(4)));

// ---------------------------------------------------------------------------
// fused prep: [0,256) feat transpose | [256,512) attn transpose |
// [512,1863) weight repack | [1863,1927) segmax.  One launch, no deps.
// ---------------------------------------------------------------------------
__global__ void fused_prep_kernel(const float* __restrict__ feat,
                                  const float* __restrict__ attn,
                                  const float* __restrict__ w0,
                                  const float* __restrict__ w1,
                                  const float* __restrict__ w2,
                                  const float* __restrict__ w3,
                                  const float* __restrict__ w4,
                                  _Float16* __restrict__ featT,
                                  float* __restrict__ attnT,
                                  _Float16* __restrict__ w0F,
                                  _Float16* __restrict__ wF123,
                                  float* __restrict__ w4T,
                                  float* __restrict__ w0tail,
                                  int* __restrict__ segm)
{
  __shared__ float t[64][65];
  int blk = blockIdx.x;
  int tid = threadIdx.x;

  if (blk < 256) {                       // ---- feat (B,D,H,W) -> featT[b][y][x][c]
    int b = blk >> 6, y = blk & 63;
    for (int p = 0; p < 16; ++p) {
      int c = p * 4 + (tid >> 6), x = tid & 63;
      t[c][x] = feat[(((size_t)b * 64 + c) << 12) + (y << 6) + x];
    }
    __syncthreads();
    for (int p = 0; p < 16; ++p) {
      int x = p * 4 + (tid >> 6), c = tid & 63;
      featT[((((size_t)b * 64 + y) * 64 + x) << 6) + c] = (_Float16)t[c][x];
    }
    return;
  }
  blk -= 256;
  if (blk < 256) {                       // ---- attn (B,HW,S) -> attnT (B,S,HW)
    int b = blk >> 6, j0 = (blk & 63) << 6;
    for (int idx = tid; idx < 4096; idx += 256) {
      int r = idx >> 6, c = idx & 63;
      t[r][c] = attn[((size_t)(b * 4096 + j0 + r)) * 64 + c];
    }
    __syncthreads();
    for (int idx = tid; idx < 4096; idx += 256) {
      int s = idx >> 6, r = idx & 63;
      attnT[((size_t)(b * 64 + s)) * 4096 + j0 + r] = t[r][s];
    }
    return;
  }
  blk -= 256;
  if (blk < 1351) {                      // ---- fragment-linear weights
    int i = blk * 256 + tid;
    if (i < 147456) {                    // w0F
      int g = i / 36864, rem = i - g * 36864;
      int ks = rem >> 11, rem2 = rem & 2047;
      int cb = rem2 >> 9, e = rem2 & 511;
      int lane = e >> 3, j = e & 7;
      int n = g * 64 + cb * 16 + (lane & 15);
      int k = ks * 32 + (lane >> 4) * 8 + j;       // reordered k = kk*64+cc
      int kk = k >> 6, cc = k & 63;
      w0F[i] = (_Float16)w0[(cc * 9 + kk) * 256 + n];
      return;
    }
    i -= 147456;
    if (i < 196608) {                    // wF123
      int l = i >> 16, rem = i & 65535;
      int g = rem >> 14, rem2 = rem & 16383;
      int ks = rem2 >> 11, rem3 = rem2 & 2047;
      int cb = rem3 >> 9, e = rem3 & 511;
      int lane = e >> 3, j = e & 7;
      int n = g * 64 + cb * 16 + (lane & 15);
      int k = ks * 32 + (lane >> 4) * 8 + j;
      const float* w = (l == 0) ? w1 : (l == 1) ? w2 : w3;
      wF123[i] = (_Float16)w[k * 256 + n];
      return;
    }
    i -= 196608;
    if (i < 768) { int j = i / 256, c = i - j * 256; w4T[i] = w4[c * 3 + j]; return; }
    i -= 768;
    if (i < 1024) { int j = i >> 8, n = i & 255; w0tail[i] = w0[(576 + j) * 256 + n]; }
    return;
  }
  blk -= 1351;
  {                                      // ---- segmax (64 blocks)
    int p = blk * 256 + tid;
    if (p >= B_ * HW_) return;
    const float* a = attn + (size_t)p * S_;
    float best = a[0]; int bi = 0;
    for (int s = 1; s < S_; ++s) { float v = a[s]; if (v > best) { best = v; bi = s; } }
    segm[p] = bi;
  }
}

// ---------------------------------------------------------------------------
// topk: per (b,s) block, top-4 over 4096 pixels, reading coalesced attnT.
// ---------------------------------------------------------------------------
__global__ void topk_kernel(const float* __restrict__ attnT,
                            int* __restrict__ refc, float* __restrict__ wprob)
{
  int bid = blockIdx.x;                 // b*64 + s
  int tid = threadIdx.x;
  __shared__ float sv[256]; __shared__ int si[256];
  __shared__ float cvs[4]; __shared__ int cis[4];

  const float* col = attnT + (size_t)bid * 4096;
  float tv[4] = { -INFINITY, -INFINITY, -INFINITY, -INFINITY };
  int   ti[4] = { 0x7fffffff, 0x7fffffff, 0x7fffffff, 0x7fffffff };
  for (int j = tid; j < HW_; j += 256) {
    float v = col[j];
    if (v > tv[3]) {                    // equal value: existing (lower idx) wins
      tv[3] = v; ti[3] = j;
      #pragma unroll
      for (int x = 3; x > 0; --x) {
        if (tv[x] > tv[x-1] || (tv[x] == tv[x-1] && ti[x] < ti[x-1])) {
          float fv = tv[x]; tv[x] = tv[x-1]; tv[x-1] = fv;
          int   fi = ti[x]; ti[x] = ti[x-1]; ti[x-1] = fi;
        }
      }
    }
  }
  int ptr = 0;
  for (int r = 0; r < 4; ++r) {
    sv[tid] = (ptr < 4) ? tv[ptr] : -INFINITY;
    si[tid] = (ptr < 4) ? ti[ptr] : 0x7fffffff;
    __syncthreads();
    for (int o = 128; o; o >>= 1) {
      if (tid < o) {
        float v2 = sv[tid + o]; int i2 = si[tid + o];
        if (v2 > sv[tid] || (v2 == sv[tid] && i2 < si[tid])) { sv[tid] = v2; si[tid] = i2; }
      }
      __syncthreads();
    }
    if (tid == 0) { cvs[r] = sv[0]; cis[r] = si[0]; }
    __syncthreads();
    if (ptr < 4 && ti[ptr] == cis[r]) ptr++;
    __syncthreads();
  }
  if (tid == 0) {
    float ssum = cvs[0] + cvs[1] + cvs[2] + cvs[3];
    for (int k = 0; k < 4; ++k) { refc[bid*4 + k] = cis[k]; wprob[bid*4 + k] = cvs[k] / ssum; }
  }
}

// ---------------------------------------------------------------------------
// meta: per query build 8 MLP-row descriptors {src pixel-row, tail t[4], weight}
// ---------------------------------------------------------------------------
__global__ void meta_kernel(const float* __restrict__ coord, const float* __restrict__ cell,
                            const int* __restrict__ segm, const int* __restrict__ refc,
                            const float* __restrict__ wprob,
                            int* __restrict__ msrc, float4* __restrict__ mt,
                            float* __restrict__ mwgt)
{
  int q = blockIdx.x * 256 + threadIdx.x;
  if (q >= NQ_) return;
  int b = q >> 13;
  float c0 = coord[2*q], c1 = coord[2*q + 1];
  float rc0 = cell[2*q] * 64.0f, rc1 = cell[2*q + 1] * 64.0f;   // rel_cell

  // ---- attention branch ----
  float pf0 = (c0 + 1.0f) / 2.0f * 64.0f;
  float pf1 = (c1 + 1.0f) / 2.0f * 64.0f;
  int pc0 = (int)pf0, pc1 = (int)pf1;           // trunc (non-negative)
  pc0 = min(max(pc0, 0), 4095); pc1 = min(max(pc1, 0), 4095);
  int pc1d = pc0 * 64 + pc1;
  int sg = segm[b * 4096 + min(pc1d, 4095)];
  int base = (b * 64 + sg) * 4;
  #pragma unroll
  for (int k = 0; k < 4; ++k) {
    int rc = refc[base + k];
    int rrc = rc - pc1d;
    float rel0 = (float)(rrc >> 6) * 0.015625f;   // floor-div by 64 then /64
    float rel1 = (float)(rrc & 63) * 0.015625f;
    int r = q * 8 + k;
    msrc[r] = rc;                                  // batch-0 gather (faithful)
    mt[r] = make_float4(rel0, rel1, rc0, rc1);
    mwgt[r] = 0.5f * wprob[base + k];
  }

  // ---- local ensemble branch ----
  const float sg0[4] = { -1.f, -1.f, 1.f, 1.f };
  const float sg1[4] = { -1.f,  1.f, -1.f, 1.f };
  float area[4], rr0[4], rr1[4]; int srcs[4];
  #pragma unroll
  for (int t = 0; t < 4; ++t) {
    float o0 = sg0[t] * 0.015625f + 1e-6f;
    float o1 = sg1[t] * 0.015625f + 1e-6f;
    float cc0 = fminf(fmaxf(c0 + o0, -1.0f + 1e-6f), 1.0f - 1e-6f);
    float cc1 = fminf(fmaxf(c1 + o1, -1.0f + 1e-6f), 1.0f - 1e-6f);
    float vy = ((cc0 + 1.0f) * 64.0f - 1.0f) / 2.0f;
    float vx = ((cc1 + 1.0f) * 64.0f - 1.0f) / 2.0f;
    float fy = fminf(fmaxf(rintf(vy), 0.0f), 63.0f);   // rint (RNE) then clip
    float fx = fminf(fmaxf(rintf(vx), 0.0f), 63.0f);
    int iy = (int)fy, ix = (int)fx;
    srcs[t] = b * 4096 + iy * 64 + ix;
    float qc0 = -1.0f + (2.0f * (float)iy + 1.0f) / 64.0f;
    float qc1 = -1.0f + (2.0f * (float)ix + 1.0f) / 64.0f;
    float r0 = (c0 - qc0) * 64.0f;
    float r1 = (c1 - qc1) * 64.0f;
    rr0[t] = r0; rr1[t] = r1;
    area[t] = fabsf(r0 * r1) + 1e-9f;
  }
  float tot = area[0] + area[1] + area[2] + area[3];
  #pragma unroll
  for (int t = 0; t < 4; ++t) {
    int r = q * 8 + 4 + t;
    msrc[r] = srcs[t];
    mt[r] = make_float4(rr0[t], rr1[t], rc0, rc1);
    mwgt[r] = 0.5f * area[3 - t] / tot;            // wts = area[::-1]/tot
  }
}

// ---------------------------------------------------------------------------
// P0 GEMM (f16 MFMA, f16 output): 256 blocks = one image row (64 px) each;
// 4x less weight re-streaming than 16-px blocks; 2 blocks/CU.
// ---------------------------------------------------------------------------
__launch_bounds__(256, 2)
__global__ void p0_kernel(const _Float16* __restrict__ featT,
                          const _Float16* __restrict__ w0F,
                          _Float16* __restrict__ P0h)
{
  int blk = blockIdx.x;                 // b*64 + y
  int b = blk >> 6, y = blk & 63;
  int tid = threadIdx.x;
  int wave = tid >> 6, lane = tid & 63, quad = lane >> 4, l16 = lane & 15;

  f32x4 acc[4][4];
  #pragma unroll
  for (int i = 0; i < 4; i++)
    #pragma unroll
    for (int j = 0; j < 4; j++) { f32x4 z = {0.f,0.f,0.f,0.f}; acc[i][j] = z; }
  h8 zero8 = {0,0,0,0,0,0,0,0};

  #pragma unroll
  for (int ks = 0; ks < 18; ++ks) {     // K = 576 = 18*32
    int k0 = ks * 32 + quad * 8;
    int kk = k0 >> 6, cc = k0 & 63;
    int di = kk / 3 - 1, dj = kk - (kk / 3) * 3 - 1;
    int yy = y + di;
    h8 afr[4];
    #pragma unroll
    for (int rb = 0; rb < 4; rb++) {
      int xx = rb * 16 + l16 + dj;
      if ((unsigned)yy < 64u && (unsigned)xx < 64u)
        afr[rb] = *(const h8*)(featT + ((((size_t)b * 64 + yy) * 64 + xx) << 6) + cc);
      else
        afr[rb] = zero8;
    }
    h8 bfr[4];
    #pragma unroll
    for (int cb = 0; cb < 4; cb++)
      bfr[cb] = *(const h8*)(w0F + ((((size_t)wave * 18 + ks) * 4 + cb) << 9) + lane * 8);
    #pragma unroll
    for (int rb = 0; rb < 4; rb++)
      #pragma unroll
      for (int cb = 0; cb < 4; cb++)
        acc[rb][cb] = __builtin_amdgcn_mfma_f32_16x16x32_f16(afr[rb], bfr[cb], acc[rb][cb], 0, 0, 0);
  }
  int pixbase = blk * 64;
  #pragma unroll
  for (int rb = 0; rb < 4; rb++)
    #pragma unroll
    for (int cb = 0; cb < 4; cb++)
      #pragma unroll
      for (int i = 0; i < 4; i++) {
        int m = rb * 16 + quad * 4 + i;
        int n = wave * 64 + cb * 16 + l16;
        P0h[((size_t)(pixbase + m) << 8) + n] = (_Float16)acc[rb][cb][i];
      }
}

// ---------------------------------------------------------------------------
// Fused MLP trunk, M=128 tile (f16 MFMA): seed (f16 P0 gather) -> 3 layers
// (in-place LDS) -> epilogue v2: weighted-row-combine FIRST (256-dim per
// query), then one 256->3 matvec per query (4x less epilogue VALU).
// ---------------------------------------------------------------------------
__launch_bounds__(256, 2)
__global__ void trunk_kernel(const _Float16* __restrict__ P0h,
                             const int* __restrict__ msrc,
                             const float4* __restrict__ mt,
                             const float* __restrict__ mwgt,
                             const float* __restrict__ w0tail,
                             const float* __restrict__ b0,
                             const _Float16* __restrict__ wF123,
                             const float* __restrict__ b1,
                             const float* __restrict__ b2,
                             const float* __restrict__ b3,
                             const float* __restrict__ w4T,
                             const float* __restrict__ b4,
                             float* __restrict__ out)
{
  __shared__ _Float16 hS[128][264];     // +8 pad; 67.6 KB
  __shared__ float mwL[128];
  __shared__ float swL[16];
  __shared__ float partB[16][3][4];

  int tid = threadIdx.x;
  int rowbase = blockIdx.x * 128;
  int wv = tid >> 6;

  if (tid < 128) mwL[tid] = mwgt[rowbase + tid];

  // ---- seed: h0 = relu(P0h[src] + t . w0tail + b0); 8-deep batched gather ----
  {
    int cg = tid & 63;
    float4 wt0 = ((const float4*)w0tail)[cg];
    float4 wt1 = ((const float4*)w0tail)[64 + cg];
    float4 wt2 = ((const float4*)w0tail)[128 + cg];
    float4 wt3 = ((const float4*)w0tail)[192 + cg];
    float4 bb  = ((const float4*)b0)[cg];
    #pragma unroll 1
    for (int g = 0; g < 4; ++g) {
      int srcs[8]; float4 ts[8];
      #pragma unroll
      for (int i = 0; i < 8; ++i) {
        int r = rowbase + g * 32 + i * 4 + wv;
        srcs[i] = msrc[r];
        ts[i] = mt[r];
      }
      #pragma unroll
      for (int i = 0; i < 8; ++i) {
        int rr = g * 32 + i * 4 + wv;
        float4 t = ts[i];
        h4 pv = *(const h4*)(P0h + ((size_t)srcs[i] << 8) + cg * 4);
        h4 v;
        v[0] = (_Float16)fmaxf((float)pv[0] + t.x*wt0.x + t.y*wt1.x + t.z*wt2.x + t.w*wt3.x + bb.x, 0.0f);
        v[1] = (_Float16)fmaxf((float)pv[1] + t.x*wt0.y + t.y*wt1.y + t.z*wt2.y + t.w*wt3.y + bb.y, 0.0f);
        v[2] = (_Float16)fmaxf((float)pv[2] + t.x*wt0.z + t.y*wt1.z + t.z*wt2.z + t.w*wt3.z + bb.z, 0.0f);
        v[3] = (_Float16)fmaxf((float)pv[3] + t.x*wt0.w + t.y*wt1.w + t.z*wt2.w + t.w*wt3.w + bb.w, 0.0f);
        *(h4*)(&hS[rr][cg * 4]) = v;
      }
    }
  }
  __syncthreads();

  int wave = tid >> 6, lane = tid & 63, quad = lane >> 4, l16 = lane & 15;

  #pragma unroll 1
  for (int l = 0; l < 3; ++l) {
    const _Float16* wL = wF123 + (((size_t)l * 4 + wave) << 14);
    const float* bia = (l == 0) ? b1 : (l == 1) ? b2 : b3;
    f32x4 acc[8][4];
    #pragma unroll
    for (int i = 0; i < 8; i++)
      #pragma unroll
      for (int j = 0; j < 4; j++) { f32x4 z = {0.f,0.f,0.f,0.f}; acc[i][j] = z; }

    h8 bP[2][4];
    #pragma unroll
    for (int cb = 0; cb < 4; cb++) {    // B prefetch depth 2
      bP[0][cb] = *(const h8*)(wL + (((size_t)0 * 4 + cb) << 9) + lane * 8);
      bP[1][cb] = *(const h8*)(wL + (((size_t)1 * 4 + cb) << 9) + lane * 8);
    }

    #pragma unroll
    for (int ks = 0; ks < 8; ++ks) {
      int cur = ks & 1;
      int k0 = ks * 32 + quad * 8;
      h8 afr[8];
      #pragma unroll
      for (int rb = 0; rb < 8; rb++)
        afr[rb] = *(const h8*)(&hS[rb * 16 + l16][k0]);
      #pragma unroll
      for (int rb = 0; rb < 8; rb++)
        #pragma unroll
        for (int cb = 0; cb < 4; cb++)
          acc[rb][cb] = __builtin_amdgcn_mfma_f32_16x16x32_f16(afr[rb], bP[cur][cb], acc[rb][cb], 0, 0, 0);
      if (ks + 2 < 8) {                 // B for ks+2 into the slot just freed
        #pragma unroll
        for (int cb = 0; cb < 4; cb++)
          bP[cur][cb] = *(const h8*)(wL + (((size_t)(ks + 2) * 4 + cb) << 9) + lane * 8);
      }
    }
    __syncthreads();                    // all reads of hS complete
    #pragma unroll
    for (int rb = 0; rb < 8; rb++)
      #pragma unroll
      for (int cb = 0; cb < 4; cb++) {
        int n = wave * 64 + cb * 16 + l16;
        float bv = bia[n];
        #pragma unroll
        for (int i = 0; i < 4; i++) {
          int m = rb * 16 + quad * 4 + i;
          hS[m][n] = (_Float16)fmaxf(acc[rb][cb][i] + bv, 0.0f);   // in-place
        }
      }
    __syncthreads();                    // writes visible before next reads
  }

  // ---- epilogue v2 ----
  // Phase A: weighted row-combine per query: hsum[q][c] = sum_j wgt*h3[q*8+j][c]
  {
    int q = tid >> 4, cpart = tid & 15;          // 16 threads/query, 16 cols each
    float accq[16];
    #pragma unroll
    for (int u = 0; u < 16; ++u) accq[u] = 0.0f;
    float sw = 0.0f;
    #pragma unroll
    for (int j = 0; j < 8; ++j) {
      int row = q * 8 + j;
      float w = mwL[row];
      sw += w;
      h8 a = *(const h8*)(&hS[row][cpart * 16]);
      h8 bq = *(const h8*)(&hS[row][cpart * 16 + 8]);
      #pragma unroll
      for (int u = 0; u < 8; ++u) {
        accq[u]     += w * (float)a[u];
        accq[8 + u] += w * (float)bq[u];
      }
    }
    __syncthreads();                    // all phase-A reads of hS done
    float* hsF = (float*)&hS[0][0];     // reuse LDS as [16][256] f32
    #pragma unroll
    for (int u = 0; u < 16; u += 4)
      *(f32x4*)(hsF + q * 256 + cpart * 16 + u) =
        f32x4{accq[u], accq[u+1], accq[u+2], accq[u+3]};
    if (cpart == 0) swL[q] = sw;
  }
  __syncthreads();
  // Phase B: matvec (Σwgt·h) @ w4
  if (tid < 192) {
    int q = tid / 12, r = tid % 12, j = r >> 2, part = r & 3;
    const float* hsF = (const float*)&hS[0][0];
    const float* hp = hsF + q * 256 + part * 64;
    const float* wp = w4T + j * 256 + part * 64;
    float s = 0.0f;
    #pragma unroll
    for (int u = 0; u < 64; ++u) s += hp[u] * wp[u];
    partB[q][j][part] = s;
  }
  __syncthreads();
  if (tid < 48) {
    int q = tid / 3, j = tid % 3;
    float o = partB[q][j][0] + partB[q][j][1] + partB[q][j][2] + partB[q][j][3]
            + b4[j] * swL[q];
    out[(size_t)(blockIdx.x * 16 + q) * 3 + j] = o;
  }
}

// ---------------------------------------------------------------------------
extern "C" void kernel_launch(void* const* d_in, const int* in_sizes, int n_in,
                              void* d_out, int out_size, void* d_ws, size_t ws_size,
                              hipStream_t stream)
{
  const float* feat  = (const float*)d_in[0];
  const float* attn  = (const float*)d_in[1];
  const float* coord = (const float*)d_in[2];
  const float* cell  = (const float*)d_in[3];
  const float* w0 = (const float*)d_in[4];
  const float* b0 = (const float*)d_in[5];
  const float* w1 = (const float*)d_in[6];
  const float* b1 = (const float*)d_in[7];
  const float* w2 = (const float*)d_in[8];
  const float* b2 = (const float*)d_in[9];
  const float* w3 = (const float*)d_in[10];
  const float* b3 = (const float*)d_in[11];
  const float* w4 = (const float*)d_in[12];
  const float* b4 = (const float*)d_in[13];
  float* out = (float*)d_out;           // reference output dtype = float32

  char* ws = (char*)d_ws;
  size_t off = 0;
  auto alloc = [&](size_t bytes) -> char* {
    char* p = ws + off;
    off += (bytes + 255) & ~(size_t)255;
    return p;
  };
  _Float16* featT = (_Float16*)alloc((size_t)B_ * H_ * W_ * D_ * 2);  //  2.10 MB
  _Float16* w0F   = (_Float16*)alloc((size_t)147456 * 2);             //  0.29 MB
  _Float16* wF123 = (_Float16*)alloc((size_t)196608 * 2);             //  0.39 MB
  float*  w4T   = (float*)alloc((size_t)3 * 256 * 4);
  float*  w0tl  = (float*)alloc((size_t)4 * 256 * 4);
  float*  attnT = (float*)alloc((size_t)B_ * S_ * HW_ * 4);           //  4.2 MB
  int*    segm  = (int*)alloc((size_t)B_ * HW_ * 4);                  //  64 KB
  int*    refc  = (int*)alloc((size_t)B_ * S_ * K_ * 4);
  float*  wprob = (float*)alloc((size_t)B_ * S_ * K_ * 4);
  _Float16* P0h = (_Float16*)alloc((size_t)B_ * HW_ * 256 * 2);       //  8.4 MB
  int*    msrc  = (int*)alloc((size_t)ROWS_ * 4);                     //  1.0 MB
  float4* mtb   = (float4*)alloc((size_t)ROWS_ * 16);                 //  4.2 MB
  float*  mwgt  = (float*)alloc((size_t)ROWS_ * 4);                   //  1.0 MB
  (void)in_sizes; (void)n_in; (void)out_size; (void)ws_size;          // ~23 MB total

  fused_prep_kernel<<<1927, 256, 0, stream>>>(feat, attn, w0, w1, w2, w3, w4,
                                              featT, attnT, w0F, wF123, w4T, w0tl, segm);
  topk_kernel<<<256, 256, 0, stream>>>(attnT, refc, wprob);
  meta_kernel<<<128, 256, 0, stream>>>(coord, cell, segm, refc, wprob, msrc, mtb, mwgt);
  p0_kernel<<<256, 256, 0, stream>>>(featT, w0F, P0h);
  trunk_kernel<<<2048, 256, 0, stream>>>(P0h, msrc, mtb, mwgt, w0tl, b0, wF123,
                                         b1, b2, b3, w4T, b4, out);
}